// Round 8
// baseline (8624.820 us; speedup 1.0000x reference)
//
#include <hip/hip_runtime.h>
#include <cstddef>

#define NB 32
#define NS 64
#define NH 768
#define NSEG_ (NB*NS)      // 2048
#define NIN 816
#define G4 3072
#define HOR_ 24
#define FBLK 192           // fused persistent blocks: 96 L0 + 96 L1
#define NL0 96
#define LTHR 512           // 8 waves/block

// workspace offsets (floats)
#define OFF_X      0
#define SZ_X       (NSEG_*NIN)
#define OFF_MEAN   (OFF_X + SZ_X)
#define SZ_MEAN    (NSEG_*NH)
#define OFF_TMP    (OFF_MEAN + SZ_MEAN)
#define OFF_HSEQ0  (OFF_TMP + SZ_MEAN)
#define OFF_HSEQ1  (OFF_HSEQ0 + SZ_MEAN)
#define OFF_XG     (OFF_HSEQ1 + SZ_MEAN)
#define SZ_XG      (NSEG_*G4)
#define OFF_HZERO  (OFF_XG + SZ_XG)
#define SZ_HZERO   (NB*NH)
#define OFF_CTR    (OFF_HZERO + SZ_HZERO)   // 8 counters spread over 8 lines

// agent-scope write-through store: lands at the coherence point; later
// first-touch cached reads see it without cache-wide fences (proven r6).
__device__ __forceinline__ void coh_store_f(float* p, float v) {
  union { float f; unsigned u; } c; c.f = v;
  __hip_atomic_store((unsigned*)p, c.u, __ATOMIC_RELAXED,
                     __HIP_MEMORY_SCOPE_AGENT);
}

// ---------------------------------------------------------------------------
// Segment mean: encs [65536,768] -> mean [2048,768]
// ---------------------------------------------------------------------------
__global__ __launch_bounds__(192) void seg_mean_kernel(
    const float* __restrict__ encs, float* __restrict__ mean) {
  const int s = blockIdx.x;
  const int t = threadIdx.x;              // 0..191, 4 cols each
  const float4* base = (const float4*)(encs + (size_t)s * 32 * NH);
  float4 a = {0.f, 0.f, 0.f, 0.f};
  #pragma unroll 4
  for (int r = 0; r < 32; ++r) {
    float4 v = base[(size_t)r * (NH / 4) + t];
    a.x += v.x; a.y += v.y; a.z += v.z; a.w += v.w;
  }
  const float inv = 1.f / 32.f;
  float4 o = {a.x * inv, a.y * inv, a.z * inv, a.w * inv};
  ((float4*)mean)[(size_t)s * (NH / 4) + t] = o;
}

// ---------------------------------------------------------------------------
// C[M,N] = A[M,K] @ W[N,K]^T + bias1[n] + bias2[n]   (fp32, 64x64 tile)
// ---------------------------------------------------------------------------
__global__ __launch_bounds__(256) void gemm_nt(
    const float* __restrict__ A, const float* __restrict__ W,
    const float* __restrict__ bias1, const float* __restrict__ bias2,
    float* __restrict__ C, int M, int N, int K) {
  __shared__ float As[16][65];
  __shared__ float Ws[16][65];
  const int tid = threadIdx.x;
  const int bm = blockIdx.y, bn = blockIdx.x;
  const int tm = tid >> 4, tn = tid & 15;
  const int lr  = tid >> 2;
  const int lk4 = (tid & 3) << 2;
  float acc[4][4] = {};
  const float* Ap = A + (size_t)bm * 64 * K;
  const float* Wp = W + (size_t)bn * 64 * K;
  for (int k0 = 0; k0 < K; k0 += 16) {
    float4 av = *(const float4*)(Ap + (size_t)lr * K + k0 + lk4);
    float4 wv = *(const float4*)(Wp + (size_t)lr * K + k0 + lk4);
    __syncthreads();
    As[lk4 + 0][lr] = av.x; As[lk4 + 1][lr] = av.y;
    As[lk4 + 2][lr] = av.z; As[lk4 + 3][lr] = av.w;
    Ws[lk4 + 0][lr] = wv.x; Ws[lk4 + 1][lr] = wv.y;
    Ws[lk4 + 2][lr] = wv.z; Ws[lk4 + 3][lr] = wv.w;
    __syncthreads();
    #pragma unroll
    for (int kk = 0; kk < 16; ++kk) {
      float a0 = As[kk][tm * 4 + 0], a1 = As[kk][tm * 4 + 1];
      float a2 = As[kk][tm * 4 + 2], a3 = As[kk][tm * 4 + 3];
      float w0 = Ws[kk][tn * 4 + 0], w1 = Ws[kk][tn * 4 + 1];
      float w2 = Ws[kk][tn * 4 + 2], w3 = Ws[kk][tn * 4 + 3];
      acc[0][0] += a0 * w0; acc[0][1] += a0 * w1; acc[0][2] += a0 * w2; acc[0][3] += a0 * w3;
      acc[1][0] += a1 * w0; acc[1][1] += a1 * w1; acc[1][2] += a1 * w2; acc[1][3] += a1 * w3;
      acc[2][0] += a2 * w0; acc[2][1] += a2 * w1; acc[2][2] += a2 * w2; acc[2][3] += a2 * w3;
      acc[3][0] += a3 * w0; acc[3][1] += a3 * w1; acc[3][2] += a3 * w2; acc[3][3] += a3 * w3;
    }
  }
  const int gn = bn * 64 + tn * 4;
  float b4[4];
  #pragma unroll
  for (int j = 0; j < 4; ++j) {
    float bb = 0.f;
    if (bias1) bb += bias1[gn + j];
    if (bias2) bb += bias2[gn + j];
    b4[j] = bb;
  }
  #pragma unroll
  for (int i = 0; i < 4; ++i) {
    float* Cp = C + (size_t)(bm * 64 + tm * 4 + i) * N + gn;
    #pragma unroll
    for (int j = 0; j < 4; ++j) Cp[j] = acc[i][j] + b4[j];
  }
}

// ---------------------------------------------------------------------------
// x[s*32+b][0:816] = concat(z[b,s], cond[b,s], encoded[b*64+s])
// ---------------------------------------------------------------------------
__global__ __launch_bounds__(256) void build_x_kernel(
    const float* __restrict__ z, const float* __restrict__ cond,
    const float* __restrict__ enc, float* __restrict__ x) {
  const int idx = blockIdx.x * 256 + threadIdx.x;
  const int r = idx / NIN, c = idx % NIN;
  const int s = r >> 5, b = r & 31;
  const int bs = b * NS + s;
  float v;
  if (c < 32)      v = z[bs * 32 + c];
  else if (c < 48) v = cond[bs * 16 + (c - 32)];
  else             v = enc[(size_t)bs * NH + (c - 48)];
  x[idx] = v;
}

// ---------------------------------------------------------------------------
// Fused 2-layer persistent LSTM, software-pipelined across layers.
// 192 blocks x 512 threads: blocks [0,96) = layer 0, [96,192) = layer 1.
// Epoch e (0..64): L0 computes step e (e<64); L1 computes step e-1 (e>=1),
// with gates = Wih1 @ h0(e-1) + Whh1 @ h1(e-2) + biases (xg1 GEMM folded in).
// One shared grid barrier per epoch -> 64 barriers for BOTH layers (round-7
// post-mortem: barrier+h-visibility ~13 us/step dominates; compute ~2.6 us).
// h rotates through hseq0/hseq1 (agent write-through stores, first-touch
// cached reads -- every row written in one epoch, read in exactly one later
// epoch; round-6-proven pattern).  Wave mapping identical to round 6.
// ---------------------------------------------------------------------------
#define HP 772
__global__ __launch_bounds__(LTHR)
__attribute__((amdgpu_waves_per_eu(2, 2)))
void lstm_fused(
    const float* __restrict__ xg0,   // [64*32][3072] layer-0 input gates (biases folded)
    const float* __restrict__ Whh0,  // [3072][768]
    const float* __restrict__ Wih1,  // [3072][768]
    const float* __restrict__ Whh1,  // [3072][768]
    const float* __restrict__ bih1,  // [3072]
    const float* __restrict__ bhh1,  // [3072]
    const float* __restrict__ hzero, // [32][768] zeros
    float* __restrict__ hseq0,       // [2048][768], row = t*32+b
    float* __restrict__ hseq1,       // [2048][768], row = t*32+b
    unsigned* ctr) {                 // 8 counters at stride 16 u32, zeroed
  __shared__ float h_lds[16][HP];
  __shared__ float gs[32][33];
  const int tid  = threadIdx.x;
  const bool isL0 = (blockIdx.x < NL0);
  const int lblk = isL0 ? blockIdx.x : blockIdx.x - NL0;
  const int s    = tid & 15;         // k-slice
  const int r    = (tid >> 4) & 15;  // rows r (gate g0) and r+16 (gate g0+2)
  const int b2   = tid >> 8;         // batch parity
  const int g0   = r >> 3;
  const int jl   = r & 7;
  const int j    = lblk * 8 + jl;
  const size_t row0 = (size_t)(g0)     * NH + j;
  const size_t row1 = (size_t)(g0 + 2) * NH + j;
  const int koff = s * 4;

  // weight row bases (loads are loop-invariant; compiler manages residency --
  // round 6 showed remat-from-L2 per step is NOT the bottleneck)
  const float* W_hh = isL0 ? Whh0 : Whh1;
  const float* W_ih = Wih1;          // used only by L1

  // pointwise mapping (tid < 256): cell (jp, bp), c kept in register
  const int jp = tid >> 5;           // 0..7
  const int bp = tid & 31;
  float c_reg = 0.f;
  // L1 pointwise bias (gate order i,f,g,o)
  float bi4 = 0.f, bf4 = 0.f, bg4 = 0.f, bo4 = 0.f;
  if (!isL0 && tid < 256) {
    const int jj = lblk * 8 + jp;
    bi4 = bih1[0 * NH + jj] + bhh1[0 * NH + jj];
    bf4 = bih1[1 * NH + jj] + bhh1[1 * NH + jj];
    bg4 = bih1[2 * NH + jj] + bhh1[2 * NH + jj];
    bo4 = bih1[3 * NH + jj] + bhh1[3 * NH + jj];
  }

  for (int e = 0; e <= NS; ++e) {
    if (isL0) {
      if (e < NS) {
        const int t = e;
        const float* hRead = (t == 0) ? hzero : hseq0 + (size_t)(t - 1) * NB * NH;
        float xgv0 = 0.f, xgv1 = 0.f, xgv2 = 0.f, xgv3 = 0.f;
        if (tid < 256) {
          const float* xr = xg0 + (size_t)(t * NB + bp) * G4 + (lblk * 8 + jp);
          xgv0 = xr[0]; xgv1 = xr[NH]; xgv2 = xr[2 * NH]; xgv3 = xr[3 * NH];
        }
        float4 w0[12], w1[12];
        #pragma unroll
        for (int m = 0; m < 12; ++m) {
          w0[m] = *(const float4*)(W_hh + row0 * NH + koff + m * 64);
          w1[m] = *(const float4*)(W_hh + row1 * NH + koff + m * 64);
        }
        #pragma unroll
        for (int half = 0; half < 2; ++half) {
          for (int i = tid; i < 16 * (NH / 4); i += LTHR) {
            const int bl = i / (NH / 4), k4 = i - bl * (NH / 4);
            float4 v = *(const float4*)(hRead + (size_t)(half * 16 + bl) * NH + k4 * 4);
            *(float4*)(&h_lds[bl][k4 * 4]) = v;
          }
          __syncthreads();
          for (int i = 0; i < 8; ++i) {
            const int b = 2 * i + b2;
            float a0 = 0.f, a1 = 0.f;
            #pragma unroll
            for (int m = 0; m < 12; ++m) {
              float4 hv = *(const float4*)(&h_lds[b][koff + m * 64]);
              a0 += w0[m].x * hv.x + w0[m].y * hv.y + w0[m].z * hv.z + w0[m].w * hv.w;
              a1 += w1[m].x * hv.x + w1[m].y * hv.y + w1[m].z * hv.z + w1[m].w * hv.w;
            }
            #pragma unroll
            for (int mk = 1; mk < 16; mk <<= 1) {
              a0 += __shfl_xor(a0, mk);
              a1 += __shfl_xor(a1, mk);
            }
            if (s == 0) {
              const int gb = half * 16 + b;
              gs[r][gb]      = a0;
              gs[r + 16][gb] = a1;
            }
          }
          __syncthreads();
        }
        if (tid < 256) {
          const float iv = gs[0  + jp][bp] + xgv0;
          const float fv = gs[8  + jp][bp] + xgv1;
          const float gv = gs[16 + jp][bp] + xgv2;
          const float ov = gs[24 + jp][bp] + xgv3;
          const float si = 1.f / (1.f + expf(-iv));
          const float sf = 1.f / (1.f + expf(-fv));
          const float so = 1.f / (1.f + expf(-ov));
          c_reg = sf * c_reg + si * tanhf(gv);
          const float hnew = so * tanhf(c_reg);
          coh_store_f(&hseq0[(size_t)(t * NB + bp) * NH + lblk * 8 + jp], hnew);
        }
      }
    } else {
      if (e >= 1) {
        const int t = e - 1;
        const float* h0r = hseq0 + (size_t)t * NB * NH;
        const float* h1r = (t == 0) ? hzero : hseq1 + (size_t)(t - 1) * NB * NH;
        float4 u0[12], u1[12], w0[12], w1[12];
        #pragma unroll
        for (int m = 0; m < 12; ++m) {
          u0[m] = *(const float4*)(W_ih + row0 * NH + koff + m * 64);
          u1[m] = *(const float4*)(W_ih + row1 * NH + koff + m * 64);
          w0[m] = *(const float4*)(W_hh + row0 * NH + koff + m * 64);
          w1[m] = *(const float4*)(W_hh + row1 * NH + koff + m * 64);
        }
        #pragma unroll
        for (int half = 0; half < 2; ++half) {
          float a0[8], a1[8];
          // phase A: Wih1 . h0(t)
          for (int i = tid; i < 16 * (NH / 4); i += LTHR) {
            const int bl = i / (NH / 4), k4 = i - bl * (NH / 4);
            float4 v = *(const float4*)(h0r + (size_t)(half * 16 + bl) * NH + k4 * 4);
            *(float4*)(&h_lds[bl][k4 * 4]) = v;
          }
          __syncthreads();
          #pragma unroll
          for (int i = 0; i < 8; ++i) {
            const int b = 2 * i + b2;
            float p0 = 0.f, p1 = 0.f;
            #pragma unroll
            for (int m = 0; m < 12; ++m) {
              float4 hv = *(const float4*)(&h_lds[b][koff + m * 64]);
              p0 += u0[m].x * hv.x + u0[m].y * hv.y + u0[m].z * hv.z + u0[m].w * hv.w;
              p1 += u1[m].x * hv.x + u1[m].y * hv.y + u1[m].z * hv.z + u1[m].w * hv.w;
            }
            a0[i] = p0; a1[i] = p1;
          }
          __syncthreads();      // h_lds consumed
          // phase B: += Whh1 . h1(t-1)
          for (int i = tid; i < 16 * (NH / 4); i += LTHR) {
            const int bl = i / (NH / 4), k4 = i - bl * (NH / 4);
            float4 v = *(const float4*)(h1r + (size_t)(half * 16 + bl) * NH + k4 * 4);
            *(float4*)(&h_lds[bl][k4 * 4]) = v;
          }
          __syncthreads();
          #pragma unroll
          for (int i = 0; i < 8; ++i) {
            const int b = 2 * i + b2;
            float p0 = a0[i], p1 = a1[i];
            #pragma unroll
            for (int m = 0; m < 12; ++m) {
              float4 hv = *(const float4*)(&h_lds[b][koff + m * 64]);
              p0 += w0[m].x * hv.x + w0[m].y * hv.y + w0[m].z * hv.z + w0[m].w * hv.w;
              p1 += w1[m].x * hv.x + w1[m].y * hv.y + w1[m].z * hv.z + w1[m].w * hv.w;
            }
            #pragma unroll
            for (int mk = 1; mk < 16; mk <<= 1) {
              p0 += __shfl_xor(p0, mk);
              p1 += __shfl_xor(p1, mk);
            }
            if (s == 0) {
              const int gb = half * 16 + 2 * i + b2;
              gs[r][gb]      = p0;
              gs[r + 16][gb] = p1;
            }
          }
          __syncthreads();      // gs written; h_lds free
        }
        if (tid < 256) {
          const float iv = gs[0  + jp][bp] + bi4;
          const float fv = gs[8  + jp][bp] + bf4;
          const float gv = gs[16 + jp][bp] + bg4;
          const float ov = gs[24 + jp][bp] + bo4;
          const float si = 1.f / (1.f + expf(-iv));
          const float sf = 1.f / (1.f + expf(-fv));
          const float so = 1.f / (1.f + expf(-ov));
          c_reg = sf * c_reg + si * tanhf(gv);
          const float hnew = so * tanhf(c_reg);
          coh_store_f(&hseq1[(size_t)(t * NB + bp) * NH + lblk * 8 + jp], hnew);
        }
      }
    }
    // ---- shared grid barrier (epochs 0..63; last epoch ends the kernel) ----
    if (e < NS) {
      __syncthreads();
      if (tid == 0) {
        asm volatile("s_waitcnt vmcnt(0)" ::: "memory");
        __hip_atomic_fetch_add(&ctr[(blockIdx.x & 7) * 16], 1u,
                               __ATOMIC_RELAXED, __HIP_MEMORY_SCOPE_AGENT);
      }
      if (tid < 8) {
        const unsigned target = (unsigned)(e + 1) * (FBLK / 8);
        while (__hip_atomic_load(&ctr[tid * 16], __ATOMIC_RELAXED,
                                 __HIP_MEMORY_SCOPE_AGENT) < target)
          __builtin_amdgcn_s_sleep(1);
      }
      __syncthreads();
    }
  }
}

// ---------------------------------------------------------------------------
// preds[b*24+s] = dot(h1seq[s*32+b], Wout) + bout
// ---------------------------------------------------------------------------
__global__ __launch_bounds__(64) void head_kernel(
    const float* __restrict__ hseq1, const float* __restrict__ Wout,
    const float* __restrict__ bout, float* __restrict__ preds) {
  const int o = blockIdx.x;
  const int b = o / HOR_, s = o % HOR_;
  const int l = threadIdx.x;
  const float* h = hseq1 + (size_t)(s * NB + b) * NH;
  float acc = 0.f;
  #pragma unroll
  for (int k = l; k < NH; k += 64) acc += h[k] * Wout[k];
  #pragma unroll
  for (int m = 32; m; m >>= 1) acc += __shfl_xor(acc, m);
  if (l == 0) preds[o] = acc + bout[0];
}

// ---------------------------------------------------------------------------
extern "C" void kernel_launch(void* const* d_in, const int* in_sizes, int n_in,
                              void* d_out, int out_size, void* d_ws, size_t ws_size,
                              hipStream_t stream) {
  const float* z    = (const float*)d_in[0];
  const float* cond = (const float*)d_in[1];
  const float* encs = (const float*)d_in[2];
  const float* W1   = (const float*)d_in[4];
  const float* b1   = (const float*)d_in[5];
  const float* W2   = (const float*)d_in[6];
  const float* b2   = (const float*)d_in[7];
  const float* Wih0 = (const float*)d_in[8];
  const float* Whh0 = (const float*)d_in[9];
  const float* bih0 = (const float*)d_in[10];
  const float* bhh0 = (const float*)d_in[11];
  const float* Wih1 = (const float*)d_in[12];
  const float* Whh1 = (const float*)d_in[13];
  const float* bih1 = (const float*)d_in[14];
  const float* bhh1 = (const float*)d_in[15];
  const float* Wout = (const float*)d_in[16];
  const float* bout = (const float*)d_in[17];

  float* out     = (float*)d_out;
  float* preds   = out;
  float* enc_out = out + NB * HOR_;

  float* ws    = (float*)d_ws;
  float* xb    = ws + OFF_X;
  float* mean  = ws + OFF_MEAN;
  float* tmp   = ws + OFF_TMP;
  float* hseq0 = ws + OFF_HSEQ0;
  float* hseq1 = ws + OFF_HSEQ1;
  float* xg    = ws + OFF_XG;
  float* hzero = ws + OFF_HZERO;
  unsigned* ctr = (unsigned*)(ws + OFF_CTR);

  // 1. segment mean (filter and mean are linear and commute -> pool first)
  seg_mean_kernel<<<NSEG_, 192, 0, stream>>>(encs, mean);
  // 2. encoded = (mean @ W1^T + b1) @ W2^T + b2 -> straight into d_out
  gemm_nt<<<dim3(NH / 64, NSEG_ / 64), 256, 0, stream>>>(
      mean, W1, b1, nullptr, tmp, NSEG_, NH, NH);
  gemm_nt<<<dim3(NH / 64, NSEG_ / 64), 256, 0, stream>>>(
      tmp, W2, b2, nullptr, enc_out, NSEG_, NH, NH);
  // 3. x = concat(z, cond, encoded), time-major rows (s*32+b)
  build_x_kernel<<<(NSEG_ * NIN) / 256, 256, 0, stream>>>(z, cond, enc_out, xb);
  // 4. layer-0 input gates (biases folded in)
  gemm_nt<<<dim3(G4 / 64, NSEG_ / 64), 256, 0, stream>>>(
      xb, Wih0, bih0, bhh0, xg, NSEG_, G4, NIN);
  // 5. fused, pipelined 2-layer recurrence (layer-1 xg GEMM folded in)
  hipMemsetAsync(hzero, 0, (size_t)(SZ_HZERO + 128) * sizeof(float), stream);
  lstm_fused<<<FBLK, LTHR, 0, stream>>>(xg, Whh0, Wih1, Whh1, bih1, bhh1,
                                        hzero, hseq0, hseq1, ctr);
  // 6. head
  head_kernel<<<NB * HOR_, 64, 0, stream>>>(hseq1, Wout, bout, preds);
}

// Round 9
// 1267.971 us; speedup vs baseline: 6.8021x; 6.8021x over previous
//
#include <hip/hip_runtime.h>
#include <cstddef>

#define NB 32
#define NS 64
#define NH 768
#define NSEG_ (NB*NS)      // 2048
#define NIN 816
#define G4 3072
#define HOR_ 24
#define LBLK 96            // persistent blocks (96 CUs, 1 block/CU)
#define LTHR 512           // 8 waves/block

// MFMA fragment types (short-based bf16, per guide: compile-verified on gfx950)
typedef __attribute__((ext_vector_type(8))) short bf16x8;
typedef __attribute__((ext_vector_type(4))) float f32x4;
typedef __attribute__((ext_vector_type(8))) unsigned short u16x8;

// dynamic-LDS partition: h as bf16 hi/lo [32][776] + partial-C [4][32][33]
#define HHP 776
#define SMEM_BYTES (2*32*HHP*2 + 4*32*33*4)   // 99328 + 16896 = 116224

// workspace offsets (floats)
#define OFF_X      0
#define SZ_X       (NSEG_*NIN)
#define OFF_MEAN   (OFF_X + SZ_X)
#define SZ_MEAN    (NSEG_*NH)
#define OFF_TMP    (OFF_MEAN + SZ_MEAN)
#define OFF_HSEQ0  (OFF_TMP + SZ_MEAN)
#define OFF_HSEQ1  (OFF_HSEQ0 + SZ_MEAN)
#define OFF_XG     (OFF_HSEQ1 + SZ_MEAN)
#define SZ_XG      (NSEG_*G4)
#define OFF_HZERO  (OFF_XG + SZ_XG)
#define SZ_HZERO   (NB*NH)
#define OFF_CTR    (OFF_HZERO + SZ_HZERO)   // 8 counters spread over 8 lines

// agent-scope write-through store (coherence point; proven r6)
__device__ __forceinline__ void coh_store_f(float* p, float v) {
  union { float f; unsigned u; } c; c.f = v;
  __hip_atomic_store((unsigned*)p, c.u, __ATOMIC_RELAXED,
                     __HIP_MEMORY_SCOPE_AGENT);
}

// ---------------------------------------------------------------------------
// Segment mean: encs [65536,768] -> mean [2048,768]
// ---------------------------------------------------------------------------
__global__ __launch_bounds__(192) void seg_mean_kernel(
    const float* __restrict__ encs, float* __restrict__ mean) {
  const int s = blockIdx.x;
  const int t = threadIdx.x;
  const float4* base = (const float4*)(encs + (size_t)s * 32 * NH);
  float4 a = {0.f, 0.f, 0.f, 0.f};
  #pragma unroll 4
  for (int r = 0; r < 32; ++r) {
    float4 v = base[(size_t)r * (NH / 4) + t];
    a.x += v.x; a.y += v.y; a.z += v.z; a.w += v.w;
  }
  const float inv = 1.f / 32.f;
  float4 o = {a.x * inv, a.y * inv, a.z * inv, a.w * inv};
  ((float4*)mean)[(size_t)s * (NH / 4) + t] = o;
}

// ---------------------------------------------------------------------------
// C[M,N] = A[M,K] @ W[N,K]^T + bias1[n] + bias2[n]   (fp32, 64x64 tile)
// ---------------------------------------------------------------------------
__global__ __launch_bounds__(256) void gemm_nt(
    const float* __restrict__ A, const float* __restrict__ W,
    const float* __restrict__ bias1, const float* __restrict__ bias2,
    float* __restrict__ C, int M, int N, int K) {
  __shared__ float As[16][65];
  __shared__ float Ws[16][65];
  const int tid = threadIdx.x;
  const int bm = blockIdx.y, bn = blockIdx.x;
  const int tm = tid >> 4, tn = tid & 15;
  const int lr  = tid >> 2;
  const int lk4 = (tid & 3) << 2;
  float acc[4][4] = {};
  const float* Ap = A + (size_t)bm * 64 * K;
  const float* Wp = W + (size_t)bn * 64 * K;
  for (int k0 = 0; k0 < K; k0 += 16) {
    float4 av = *(const float4*)(Ap + (size_t)lr * K + k0 + lk4);
    float4 wv = *(const float4*)(Wp + (size_t)lr * K + k0 + lk4);
    __syncthreads();
    As[lk4 + 0][lr] = av.x; As[lk4 + 1][lr] = av.y;
    As[lk4 + 2][lr] = av.z; As[lk4 + 3][lr] = av.w;
    Ws[lk4 + 0][lr] = wv.x; Ws[lk4 + 1][lr] = wv.y;
    Ws[lk4 + 2][lr] = wv.z; Ws[lk4 + 3][lr] = wv.w;
    __syncthreads();
    #pragma unroll
    for (int kk = 0; kk < 16; ++kk) {
      float a0 = As[kk][tm * 4 + 0], a1 = As[kk][tm * 4 + 1];
      float a2 = As[kk][tm * 4 + 2], a3 = As[kk][tm * 4 + 3];
      float w0 = Ws[kk][tn * 4 + 0], w1 = Ws[kk][tn * 4 + 1];
      float w2 = Ws[kk][tn * 4 + 2], w3 = Ws[kk][tn * 4 + 3];
      acc[0][0] += a0 * w0; acc[0][1] += a0 * w1; acc[0][2] += a0 * w2; acc[0][3] += a0 * w3;
      acc[1][0] += a1 * w0; acc[1][1] += a1 * w1; acc[1][2] += a1 * w2; acc[1][3] += a1 * w3;
      acc[2][0] += a2 * w0; acc[2][1] += a2 * w1; acc[2][2] += a2 * w2; acc[2][3] += a2 * w3;
      acc[3][0] += a3 * w0; acc[3][1] += a3 * w1; acc[3][2] += a3 * w2; acc[3][3] += a3 * w3;
    }
  }
  const int gn = bn * 64 + tn * 4;
  float b4[4];
  #pragma unroll
  for (int j = 0; j < 4; ++j) {
    float bb = 0.f;
    if (bias1) bb += bias1[gn + j];
    if (bias2) bb += bias2[gn + j];
    b4[j] = bb;
  }
  #pragma unroll
  for (int i = 0; i < 4; ++i) {
    float* Cp = C + (size_t)(bm * 64 + tm * 4 + i) * N + gn;
    #pragma unroll
    for (int j = 0; j < 4; ++j) Cp[j] = acc[i][j] + b4[j];
  }
}

// ---------------------------------------------------------------------------
// x[s*32+b][0:816] = concat(z[b,s], cond[b,s], encoded[b*64+s])
// ---------------------------------------------------------------------------
__global__ __launch_bounds__(256) void build_x_kernel(
    const float* __restrict__ z, const float* __restrict__ cond,
    const float* __restrict__ enc, float* __restrict__ x) {
  const int idx = blockIdx.x * 256 + threadIdx.x;
  const int r = idx / NIN, c = idx % NIN;
  const int s = r >> 5, b = r & 31;
  const int bs = b * NS + s;
  float v;
  if (c < 32)      v = z[bs * 32 + c];
  else if (c < 48) v = cond[bs * 16 + (c - 32)];
  else             v = enc[(size_t)bs * NH + (c - 48)];
  x[idx] = v;
}

// ---------------------------------------------------------------------------
// Persistent LSTM layer with SPLIT-BF16 MFMA recurrence dot.
// 96 blocks x 512 threads (8 waves).  Block owns 8 hidden units -> 32 gate
// rows (r = g*8+jl).  gates[32x32] = Whh_blk[32x768] . h[768x32] via
// mfma_f32_16x16x32_bf16, W and h split hi/lo (3 products, ~fp32 accuracy).
// Wave w = (mt = w>>2: M-tile, kh = w&3: K-quarter of 192).  A-frags (weights)
// converted once at start: 12 bf16x8 = 48 VGPR, static across all 64 steps
// (round-8 lesson: stay far below the 128-VGPR spill cliff).
// Per step: stage h fp32 -> bf16 hi/lo in LDS; 36 MFMA/wave; partial-C
// reduced through a 17 KB LDS buffer; fp32 pointwise; h published via
// agent write-through stores; counter grid barrier (all proven r6).
// ---------------------------------------------------------------------------
__global__ __launch_bounds__(LTHR)
__attribute__((amdgpu_waves_per_eu(2, 2)))
void lstm_persist(
    const float* __restrict__ xg,    // [64*32][3072], row = t*32+b (biases folded)
    const float* __restrict__ Whh,   // [3072][768]
    const float* __restrict__ hzero, // [32][768] zeros (step-0 input)
    float* __restrict__ hseq,        // [2048][768], row = t*32+b
    unsigned* ctr) {                 // 8 counters at stride 16 u32, zeroed
  extern __shared__ __align__(16) unsigned short smem_us[];
  unsigned short* hh  = smem_us;                 // [32][HHP] bf16(h) hi
  unsigned short* hl  = smem_us + 32 * HHP;      // [32][HHP] bf16(h residual)
  float*          gsp = (float*)(smem_us + 2 * 32 * HHP);  // [4][32][33]

  const int tid  = threadIdx.x;
  const int lane = tid & 63;
  const int wid  = tid >> 6;
  const int mt   = wid >> 2;         // M-tile (rows mt*16 .. +16)
  const int kh   = wid & 3;          // K-quarter (k = kh*192 .. +192)
  const int lm   = lane & 15;
  const int lk   = lane >> 4;

  // ---- A-fragments: this lane's weight slice, split hi/lo, loaded ONCE ----
  const int rloc = mt * 16 + lm;                       // gate-row 0..31
  const int grow = (rloc >> 3) * NH + blockIdx.x * 8 + (rloc & 7);
  bf16x8 whi[6], wlo[6];
  #pragma unroll
  for (int s6 = 0; s6 < 6; ++s6) {
    const float* wp = Whh + (size_t)grow * NH + kh * 192 + s6 * 32 + lk * 8;
    float4 a = *(const float4*)wp;
    float4 b = *(const float4*)(wp + 4);
    float vv[8] = {a.x, a.y, a.z, a.w, b.x, b.y, b.z, b.w};
    #pragma unroll
    for (int i = 0; i < 8; ++i) {
      const unsigned u = __float_as_uint(vv[i]);
      const float rem = vv[i] - __uint_as_float(u & 0xffff0000u);
      whi[s6][i] = (short)(u >> 16);
      wlo[s6][i] = (short)(__float_as_uint(rem) >> 16);
    }
  }

  // pointwise mapping (tid < 256): cell (jp, bp), c kept in register
  const int jp = tid >> 5;           // 0..7
  const int bp = tid & 31;
  float c_reg = 0.f;

  // staging mapping: batch = tid>>4, chunk column = tid&15
  const int sb  = tid >> 4;          // 0..31
  const int sch = tid & 15;          // 0..15

  for (int t = 0; t < NS; ++t) {
    const float* hRead = (t == 0) ? hzero : hseq + (size_t)(t - 1) * NB * NH;
    // prefetch xg for this step's pointwise (hides under staging/MFMA)
    float xgv0 = 0.f, xgv1 = 0.f, xgv2 = 0.f, xgv3 = 0.f;
    if (tid < 256) {
      const float* xr = xg + (size_t)(t * NB + bp) * G4 + (blockIdx.x * 8 + jp);
      xgv0 = xr[0]; xgv1 = xr[NH]; xgv2 = xr[2 * NH]; xgv3 = xr[3 * NH];
    }
    // ---- stage h -> LDS as bf16 hi/lo (96 chunks of 8 per batch) ----
    #pragma unroll
    for (int it = 0; it < 6; ++it) {
      const int k0 = (sch + it * 16) * 8;
      float4 v0 = *(const float4*)(hRead + (size_t)sb * NH + k0);
      float4 v1 = *(const float4*)(hRead + (size_t)sb * NH + k0 + 4);
      float vv[8] = {v0.x, v0.y, v0.z, v0.w, v1.x, v1.y, v1.z, v1.w};
      u16x8 HI, LO;
      #pragma unroll
      for (int i = 0; i < 8; ++i) {
        const unsigned u = __float_as_uint(vv[i]);
        const float rem = vv[i] - __uint_as_float(u & 0xffff0000u);
        HI[i] = (unsigned short)(u >> 16);
        LO[i] = (unsigned short)(__float_as_uint(rem) >> 16);
      }
      *(u16x8*)(&hh[sb * HHP + k0]) = HI;
      *(u16x8*)(&hl[sb * HHP + k0]) = LO;
    }
    __syncthreads();
    // ---- MFMA: 6 K-steps x 3 split-products x 2 N-tiles ----
    f32x4 acc0 = {0.f, 0.f, 0.f, 0.f};
    f32x4 acc1 = {0.f, 0.f, 0.f, 0.f};
    #pragma unroll
    for (int s6 = 0; s6 < 6; ++s6) {
      const int kb = kh * 192 + s6 * 32 + lk * 8;
      bf16x8 bh0 = *(bf16x8*)(&hh[lm * HHP + kb]);
      bf16x8 bl0 = *(bf16x8*)(&hl[lm * HHP + kb]);
      bf16x8 bh1 = *(bf16x8*)(&hh[(16 + lm) * HHP + kb]);
      bf16x8 bl1 = *(bf16x8*)(&hl[(16 + lm) * HHP + kb]);
      acc0 = __builtin_amdgcn_mfma_f32_16x16x32_bf16(whi[s6], bh0, acc0, 0, 0, 0);
      acc0 = __builtin_amdgcn_mfma_f32_16x16x32_bf16(whi[s6], bl0, acc0, 0, 0, 0);
      acc0 = __builtin_amdgcn_mfma_f32_16x16x32_bf16(wlo[s6], bh0, acc0, 0, 0, 0);
      acc1 = __builtin_amdgcn_mfma_f32_16x16x32_bf16(whi[s6], bh1, acc1, 0, 0, 0);
      acc1 = __builtin_amdgcn_mfma_f32_16x16x32_bf16(whi[s6], bl1, acc1, 0, 0, 0);
      acc1 = __builtin_amdgcn_mfma_f32_16x16x32_bf16(wlo[s6], bh1, acc1, 0, 0, 0);
    }
    // partial C -> LDS: D row = mt*16 + lk*4 + reg, col = nt*16 + lm
    #pragma unroll
    for (int r4 = 0; r4 < 4; ++r4) {
      gsp[kh * 1056 + (mt * 16 + lk * 4 + r4) * 33 + lm]      = acc0[r4];
      gsp[kh * 1056 + (mt * 16 + lk * 4 + r4) * 33 + 16 + lm] = acc1[r4];
    }
    __syncthreads();
    // ---- pointwise (gate rows r = g*8 + jp, sum over 4 K-quarters) ----
    if (tid < 256) {
      float sum[4];
      #pragma unroll
      for (int g = 0; g < 4; ++g) {
        const int row = g * 8 + jp;
        sum[g] = gsp[0 * 1056 + row * 33 + bp] + gsp[1 * 1056 + row * 33 + bp] +
                 gsp[2 * 1056 + row * 33 + bp] + gsp[3 * 1056 + row * 33 + bp];
      }
      const float iv = sum[0] + xgv0;
      const float fv = sum[1] + xgv1;
      const float gv = sum[2] + xgv2;
      const float ov = sum[3] + xgv3;
      const float si = 1.f / (1.f + expf(-iv));
      const float sf = 1.f / (1.f + expf(-fv));
      const float so = 1.f / (1.f + expf(-ov));
      c_reg = sf * c_reg + si * tanhf(gv);
      const float hnew = so * tanhf(c_reg);
      coh_store_f(&hseq[(size_t)(t * NB + bp) * NH + blockIdx.x * 8 + jp], hnew);
    }
    // ---- grid barrier ----
    if (t < NS - 1) {
      __syncthreads();
      if (tid == 0) {
        asm volatile("s_waitcnt vmcnt(0)" ::: "memory");
        __hip_atomic_fetch_add(&ctr[(blockIdx.x & 7) * 16], 1u,
                               __ATOMIC_RELAXED, __HIP_MEMORY_SCOPE_AGENT);
      }
      if (tid < 8) {
        const unsigned target = (unsigned)(t + 1) * (LBLK / 8);
        while (__hip_atomic_load(&ctr[tid * 16], __ATOMIC_RELAXED,
                                 __HIP_MEMORY_SCOPE_AGENT) < target)
          __builtin_amdgcn_s_sleep(1);
      }
      __syncthreads();
    }
  }
}

// ---------------------------------------------------------------------------
// preds[b*24+s] = dot(h1seq[s*32+b], Wout) + bout
// ---------------------------------------------------------------------------
__global__ __launch_bounds__(64) void head_kernel(
    const float* __restrict__ hseq1, const float* __restrict__ Wout,
    const float* __restrict__ bout, float* __restrict__ preds) {
  const int o = blockIdx.x;
  const int b = o / HOR_, s = o % HOR_;
  const int l = threadIdx.x;
  const float* h = hseq1 + (size_t)(s * NB + b) * NH;
  float acc = 0.f;
  #pragma unroll
  for (int k = l; k < NH; k += 64) acc += h[k] * Wout[k];
  #pragma unroll
  for (int m = 32; m; m >>= 1) acc += __shfl_xor(acc, m);
  if (l == 0) preds[o] = acc + bout[0];
}

// ---------------------------------------------------------------------------
extern "C" void kernel_launch(void* const* d_in, const int* in_sizes, int n_in,
                              void* d_out, int out_size, void* d_ws, size_t ws_size,
                              hipStream_t stream) {
  const float* z    = (const float*)d_in[0];
  const float* cond = (const float*)d_in[1];
  const float* encs = (const float*)d_in[2];
  const float* W1   = (const float*)d_in[4];
  const float* b1   = (const float*)d_in[5];
  const float* W2   = (const float*)d_in[6];
  const float* b2   = (const float*)d_in[7];
  const float* Wih0 = (const float*)d_in[8];
  const float* Whh0 = (const float*)d_in[9];
  const float* bih0 = (const float*)d_in[10];
  const float* bhh0 = (const float*)d_in[11];
  const float* Wih1 = (const float*)d_in[12];
  const float* Whh1 = (const float*)d_in[13];
  const float* bih1 = (const float*)d_in[14];
  const float* bhh1 = (const float*)d_in[15];
  const float* Wout = (const float*)d_in[16];
  const float* bout = (const float*)d_in[17];

  float* out     = (float*)d_out;
  float* preds   = out;
  float* enc_out = out + NB * HOR_;

  float* ws    = (float*)d_ws;
  float* xb    = ws + OFF_X;
  float* mean  = ws + OFF_MEAN;
  float* tmp   = ws + OFF_TMP;
  float* hseq0 = ws + OFF_HSEQ0;
  float* hseq1 = ws + OFF_HSEQ1;
  float* xg    = ws + OFF_XG;
  float* hzero = ws + OFF_HZERO;
  unsigned* ctr = (unsigned*)(ws + OFF_CTR);

  // allow >64KB dynamic LDS for the persistent kernel
  (void)hipFuncSetAttribute(reinterpret_cast<const void*>(lstm_persist),
                            hipFuncAttributeMaxDynamicSharedMemorySize,
                            160 * 1024);

  // 1. segment mean (filter and mean are linear and commute -> pool first)
  seg_mean_kernel<<<NSEG_, 192, 0, stream>>>(encs, mean);
  // 2. encoded = (mean @ W1^T + b1) @ W2^T + b2 -> straight into d_out
  gemm_nt<<<dim3(NH / 64, NSEG_ / 64), 256, 0, stream>>>(
      mean, W1, b1, nullptr, tmp, NSEG_, NH, NH);
  gemm_nt<<<dim3(NH / 64, NSEG_ / 64), 256, 0, stream>>>(
      tmp, W2, b2, nullptr, enc_out, NSEG_, NH, NH);
  // 3. x = concat(z, cond, encoded), time-major rows (s*32+b)
  build_x_kernel<<<(NSEG_ * NIN) / 256, 256, 0, stream>>>(z, cond, enc_out, xb);
  // 4. layer-0 input gates (biases folded in)
  gemm_nt<<<dim3(G4 / 64, NSEG_ / 64), 256, 0, stream>>>(
      xb, Wih0, bih0, bhh0, xg, NSEG_, G4, NIN);
  // 5. layer-0 recurrence (persistent MFMA kernel, h rotates through hseq0)
  hipMemsetAsync(hzero, 0, (size_t)(SZ_HZERO + 128) * sizeof(float), stream);
  lstm_persist<<<LBLK, LTHR, SMEM_BYTES, stream>>>(xg, Whh0, hzero, hseq0, ctr);
  // 6. layer-1 input gates
  gemm_nt<<<dim3(G4 / 64, NSEG_ / 64), 256, 0, stream>>>(
      hseq0, Wih1, bih1, bhh1, xg, NSEG_, G4, NH);
  // 7. layer-1 recurrence
  hipMemsetAsync(hzero, 0, (size_t)(SZ_HZERO + 128) * sizeof(float), stream);
  lstm_persist<<<LBLK, LTHR, SMEM_BYTES, stream>>>(xg, Whh1, hzero, hseq1, ctr);
  // 8. head
  head_kernel<<<NB * HOR_, 64, 0, stream>>>(hseq1, Wout, bout, preds);
}

// Round 10
// 890.413 us; speedup vs baseline: 9.6863x; 1.4240x over previous
//
#include <hip/hip_runtime.h>
#include <cstddef>

#define NB 32
#define NS 64
#define NH 768
#define NSEG_ (NB*NS)      // 2048
#define NIN 816
#define G4 3072
#define HOR_ 24
#define LBLK 96            // persistent blocks (96 CUs, 1 block/CU)
#define LTHR 512           // 8 waves/block

// MFMA fragment types (short-based bf16, compile-verified on gfx950)
typedef __attribute__((ext_vector_type(8))) short bf16x8;
typedef __attribute__((ext_vector_type(4))) float f32x4;
typedef __attribute__((ext_vector_type(8))) unsigned short u16x8;

// lstm dynamic-LDS partition: h as bf16 hi/lo [32][776] + partial-C [4][32][33]
#define HHP 776
#define SMEM_BYTES (2*32*HHP*2 + 4*32*33*4)   // 99328 + 16896 = 116224

// workspace offsets (floats)
#define OFF_X      0
#define SZ_X       (NSEG_*NIN)
#define OFF_MEAN   (OFF_X + SZ_X)
#define SZ_MEAN    (NSEG_*NH)
#define OFF_TMP    (OFF_MEAN + SZ_MEAN)
#define OFF_HSEQ0  (OFF_TMP + SZ_MEAN)
#define OFF_HSEQ1  (OFF_HSEQ0 + SZ_MEAN)
#define OFF_XG     (OFF_HSEQ1 + SZ_MEAN)
#define SZ_XG      (NSEG_*G4)
#define OFF_HZERO  (OFF_XG + SZ_XG)
#define SZ_HZERO   (NB*NH)
#define OFF_CTR    (OFF_HZERO + SZ_HZERO)   // 8 counters spread over 8 lines

// agent-scope write-through store (coherence point; proven r6)
__device__ __forceinline__ void coh_store_f(float* p, float v) {
  union { float f; unsigned u; } c; c.f = v;
  __hip_atomic_store((unsigned*)p, c.u, __ATOMIC_RELAXED,
                     __HIP_MEMORY_SCOPE_AGENT);
}

// split a float into bf16 hi + bf16 residual
__device__ __forceinline__ void split_bf16(float v, unsigned short& hi,
                                           unsigned short& lo) {
  const unsigned u = __float_as_uint(v);
  hi = (unsigned short)(u >> 16);
  const float rem = v - __uint_as_float(u & 0xffff0000u);
  lo = (unsigned short)(__float_as_uint(rem) >> 16);
}

// ---------------------------------------------------------------------------
// Segment mean: encs [65536,768] -> mean [2048,768]
// ---------------------------------------------------------------------------
__global__ __launch_bounds__(192) void seg_mean_kernel(
    const float* __restrict__ encs, float* __restrict__ mean) {
  const int s = blockIdx.x;
  const int t = threadIdx.x;
  const float4* base = (const float4*)(encs + (size_t)s * 32 * NH);
  float4 a = {0.f, 0.f, 0.f, 0.f};
  #pragma unroll 4
  for (int r = 0; r < 32; ++r) {
    float4 v = base[(size_t)r * (NH / 4) + t];
    a.x += v.x; a.y += v.y; a.z += v.z; a.w += v.w;
  }
  const float inv = 1.f / 32.f;
  float4 o = {a.x * inv, a.y * inv, a.z * inv, a.w * inv};
  ((float4*)mean)[(size_t)s * (NH / 4) + t] = o;
}

// ---------------------------------------------------------------------------
// Split-bf16 MFMA GEMM: C[M,N] = A[M,K] @ W[N,K]^T + bias1[n] + bias2[n]
// 3 products (hi.hi + hi.lo + lo.hi) -> ~fp32 accuracy (rel err ~2^-16).
// 64x64 tile, 256 threads = 4 waves; wave w owns rows [w*16, w*16+16).
// Stage per K=32 step: A/W tiles as bf16 hi/lo in LDS, stride 40 u16
// (16B-aligned b128, conflict-light).  K multiple of 8 (full-or-zero 8-chunk
// guard handles K=816); M,N multiples of 64.
// ---------------------------------------------------------------------------
__global__ __launch_bounds__(256) void gemm_mfma_nt(
    const float* __restrict__ A, const float* __restrict__ W,
    const float* __restrict__ bias1, const float* __restrict__ bias2,
    float* __restrict__ C, int M, int N, int K) {
  __shared__ unsigned short Ahi[64 * 40];
  __shared__ unsigned short Alo[64 * 40];
  __shared__ unsigned short Whi[64 * 40];
  __shared__ unsigned short Wlo[64 * 40];
  const int tid = threadIdx.x;
  const int bm = blockIdx.y, bn = blockIdx.x;
  const int lane = tid & 63;
  const int wid  = tid >> 6;
  const int lm = lane & 15;
  const int lk = lane >> 4;
  const int srow = tid >> 2;             // staging row 0..63
  const int skc  = (tid & 3) * 8;        // staging k-chunk {0,8,16,24}

  const float* Ap = A + (size_t)(bm * 64 + srow) * K;
  const float* Wp = W + (size_t)(bn * 64 + srow) * K;

  f32x4 acc[4];
  #pragma unroll
  for (int nf = 0; nf < 4; ++nf) acc[nf] = (f32x4){0.f, 0.f, 0.f, 0.f};

  for (int k0 = 0; k0 < K; k0 += 32) {
    // guarded load (chunk fully valid or fully out -> zeros)
    float va[8], vw[8];
    if (k0 + skc + 8 <= K) {
      float4 a0 = *(const float4*)(Ap + k0 + skc);
      float4 a1 = *(const float4*)(Ap + k0 + skc + 4);
      float4 w0 = *(const float4*)(Wp + k0 + skc);
      float4 w1 = *(const float4*)(Wp + k0 + skc + 4);
      va[0]=a0.x; va[1]=a0.y; va[2]=a0.z; va[3]=a0.w;
      va[4]=a1.x; va[5]=a1.y; va[6]=a1.z; va[7]=a1.w;
      vw[0]=w0.x; vw[1]=w0.y; vw[2]=w0.z; vw[3]=w0.w;
      vw[4]=w1.x; vw[5]=w1.y; vw[6]=w1.z; vw[7]=w1.w;
    } else {
      #pragma unroll
      for (int i = 0; i < 8; ++i) { va[i] = 0.f; vw[i] = 0.f; }
    }
    u16x8 AH, AL, WH, WL;
    #pragma unroll
    for (int i = 0; i < 8; ++i) {
      unsigned short h, l;
      split_bf16(va[i], h, l); AH[i] = h; AL[i] = l;
      split_bf16(vw[i], h, l); WH[i] = h; WL[i] = l;
    }
    __syncthreads();     // previous iteration's frag reads done
    *(u16x8*)(&Ahi[srow * 40 + skc]) = AH;
    *(u16x8*)(&Alo[srow * 40 + skc]) = AL;
    *(u16x8*)(&Whi[srow * 40 + skc]) = WH;
    *(u16x8*)(&Wlo[srow * 40 + skc]) = WL;
    __syncthreads();
    // MFMA: A-frag rows wid*16+lm; B-frags cols nf*16+lm
    bf16x8 ah = *(bf16x8*)(&Ahi[(wid * 16 + lm) * 40 + lk * 8]);
    bf16x8 al = *(bf16x8*)(&Alo[(wid * 16 + lm) * 40 + lk * 8]);
    #pragma unroll
    for (int nf = 0; nf < 4; ++nf) {
      bf16x8 bh = *(bf16x8*)(&Whi[(nf * 16 + lm) * 40 + lk * 8]);
      bf16x8 bl = *(bf16x8*)(&Wlo[(nf * 16 + lm) * 40 + lk * 8]);
      acc[nf] = __builtin_amdgcn_mfma_f32_16x16x32_bf16(ah, bh, acc[nf], 0, 0, 0);
      acc[nf] = __builtin_amdgcn_mfma_f32_16x16x32_bf16(ah, bl, acc[nf], 0, 0, 0);
      acc[nf] = __builtin_amdgcn_mfma_f32_16x16x32_bf16(al, bh, acc[nf], 0, 0, 0);
    }
  }
  // write: D[row = wid*16 + lk*4 + r][col = nf*16 + lm]
  #pragma unroll
  for (int nf = 0; nf < 4; ++nf) {
    const int gn = bn * 64 + nf * 16 + lm;
    float bb = 0.f;
    if (bias1) bb += bias1[gn];
    if (bias2) bb += bias2[gn];
    #pragma unroll
    for (int r4 = 0; r4 < 4; ++r4) {
      const int gm = bm * 64 + wid * 16 + lk * 4 + r4;
      C[(size_t)gm * N + gn] = acc[nf][r4] + bb;
    }
  }
}

// ---------------------------------------------------------------------------
// x[s*32+b][0:816] = concat(z[b,s], cond[b,s], encoded[b*64+s])
// ---------------------------------------------------------------------------
__global__ __launch_bounds__(256) void build_x_kernel(
    const float* __restrict__ z, const float* __restrict__ cond,
    const float* __restrict__ enc, float* __restrict__ x) {
  const int idx = blockIdx.x * 256 + threadIdx.x;
  const int r = idx / NIN, c = idx % NIN;
  const int s = r >> 5, b = r & 31;
  const int bs = b * NS + s;
  float v;
  if (c < 32)      v = z[bs * 32 + c];
  else if (c < 48) v = cond[bs * 16 + (c - 32)];
  else             v = enc[(size_t)bs * NH + (c - 48)];
  x[idx] = v;
}

// ---------------------------------------------------------------------------
// Persistent LSTM layer with SPLIT-BF16 MFMA recurrence dot (round-9 proven).
// ---------------------------------------------------------------------------
__global__ __launch_bounds__(LTHR)
__attribute__((amdgpu_waves_per_eu(2, 2)))
void lstm_persist(
    const float* __restrict__ xg,    // [64*32][3072], row = t*32+b (biases folded)
    const float* __restrict__ Whh,   // [3072][768]
    const float* __restrict__ hzero, // [32][768] zeros (step-0 input)
    float* __restrict__ hseq,        // [2048][768], row = t*32+b
    unsigned* ctr) {                 // 8 counters at stride 16 u32, zeroed
  extern __shared__ __align__(16) unsigned short smem_us[];
  unsigned short* hh  = smem_us;                 // [32][HHP] bf16(h) hi
  unsigned short* hl  = smem_us + 32 * HHP;      // [32][HHP] bf16(h residual)
  float*          gsp = (float*)(smem_us + 2 * 32 * HHP);  // [4][32][33]

  const int tid  = threadIdx.x;
  const int lane = tid & 63;
  const int wid  = tid >> 6;
  const int mt   = wid >> 2;         // M-tile (rows mt*16 .. +16)
  const int kh   = wid & 3;          // K-quarter (k = kh*192 .. +192)
  const int lm   = lane & 15;
  const int lk   = lane >> 4;

  // ---- A-fragments: this lane's weight slice, split hi/lo, loaded ONCE ----
  const int rloc = mt * 16 + lm;                       // gate-row 0..31
  const int grow = (rloc >> 3) * NH + blockIdx.x * 8 + (rloc & 7);
  bf16x8 whi[6], wlo[6];
  #pragma unroll
  for (int s6 = 0; s6 < 6; ++s6) {
    const float* wp = Whh + (size_t)grow * NH + kh * 192 + s6 * 32 + lk * 8;
    float4 a = *(const float4*)wp;
    float4 b = *(const float4*)(wp + 4);
    float vv[8] = {a.x, a.y, a.z, a.w, b.x, b.y, b.z, b.w};
    #pragma unroll
    for (int i = 0; i < 8; ++i) {
      unsigned short h, l;
      split_bf16(vv[i], h, l);
      whi[s6][i] = (short)h;
      wlo[s6][i] = (short)l;
    }
  }

  // pointwise mapping (tid < 256): cell (jp, bp), c kept in register
  const int jp = tid >> 5;           // 0..7
  const int bp = tid & 31;
  float c_reg = 0.f;

  // staging mapping: batch = tid>>4, chunk column = tid&15
  const int sb  = tid >> 4;          // 0..31
  const int sch = tid & 15;          // 0..15

  for (int t = 0; t < NS; ++t) {
    const float* hRead = (t == 0) ? hzero : hseq + (size_t)(t - 1) * NB * NH;
    // prefetch xg for this step's pointwise (hides under staging/MFMA)
    float xgv0 = 0.f, xgv1 = 0.f, xgv2 = 0.f, xgv3 = 0.f;
    if (tid < 256) {
      const float* xr = xg + (size_t)(t * NB + bp) * G4 + (blockIdx.x * 8 + jp);
      xgv0 = xr[0]; xgv1 = xr[NH]; xgv2 = xr[2 * NH]; xgv3 = xr[3 * NH];
    }
    // ---- stage h -> LDS as bf16 hi/lo (96 chunks of 8 per batch) ----
    #pragma unroll
    for (int it = 0; it < 6; ++it) {
      const int k0 = (sch + it * 16) * 8;
      float4 v0 = *(const float4*)(hRead + (size_t)sb * NH + k0);
      float4 v1 = *(const float4*)(hRead + (size_t)sb * NH + k0 + 4);
      float vv[8] = {v0.x, v0.y, v0.z, v0.w, v1.x, v1.y, v1.z, v1.w};
      u16x8 HI, LO;
      #pragma unroll
      for (int i = 0; i < 8; ++i) {
        unsigned short h, l;
        split_bf16(vv[i], h, l);
        HI[i] = h; LO[i] = l;
      }
      *(u16x8*)(&hh[sb * HHP + k0]) = HI;
      *(u16x8*)(&hl[sb * HHP + k0]) = LO;
    }
    __syncthreads();
    // ---- MFMA: 6 K-steps x 3 split-products x 2 N-tiles ----
    f32x4 acc0 = {0.f, 0.f, 0.f, 0.f};
    f32x4 acc1 = {0.f, 0.f, 0.f, 0.f};
    #pragma unroll
    for (int s6 = 0; s6 < 6; ++s6) {
      const int kb = kh * 192 + s6 * 32 + lk * 8;
      bf16x8 bh0 = *(bf16x8*)(&hh[lm * HHP + kb]);
      bf16x8 bl0 = *(bf16x8*)(&hl[lm * HHP + kb]);
      bf16x8 bh1 = *(bf16x8*)(&hh[(16 + lm) * HHP + kb]);
      bf16x8 bl1 = *(bf16x8*)(&hl[(16 + lm) * HHP + kb]);
      acc0 = __builtin_amdgcn_mfma_f32_16x16x32_bf16(whi[s6], bh0, acc0, 0, 0, 0);
      acc0 = __builtin_amdgcn_mfma_f32_16x16x32_bf16(whi[s6], bl0, acc0, 0, 0, 0);
      acc0 = __builtin_amdgcn_mfma_f32_16x16x32_bf16(wlo[s6], bh0, acc0, 0, 0, 0);
      acc1 = __builtin_amdgcn_mfma_f32_16x16x32_bf16(whi[s6], bh1, acc1, 0, 0, 0);
      acc1 = __builtin_amdgcn_mfma_f32_16x16x32_bf16(whi[s6], bl1, acc1, 0, 0, 0);
      acc1 = __builtin_amdgcn_mfma_f32_16x16x32_bf16(wlo[s6], bh1, acc1, 0, 0, 0);
    }
    // partial C -> LDS: D row = mt*16 + lk*4 + reg, col = nt*16 + lm
    #pragma unroll
    for (int r4 = 0; r4 < 4; ++r4) {
      gsp[kh * 1056 + (mt * 16 + lk * 4 + r4) * 33 + lm]      = acc0[r4];
      gsp[kh * 1056 + (mt * 16 + lk * 4 + r4) * 33 + 16 + lm] = acc1[r4];
    }
    __syncthreads();
    // ---- pointwise (gate rows r = g*8 + jp, sum over 4 K-quarters) ----
    if (tid < 256) {
      float sum[4];
      #pragma unroll
      for (int g = 0; g < 4; ++g) {
        const int row = g * 8 + jp;
        sum[g] = gsp[0 * 1056 + row * 33 + bp] + gsp[1 * 1056 + row * 33 + bp] +
                 gsp[2 * 1056 + row * 33 + bp] + gsp[3 * 1056 + row * 33 + bp];
      }
      const float iv = sum[0] + xgv0;
      const float fv = sum[1] + xgv1;
      const float gv = sum[2] + xgv2;
      const float ov = sum[3] + xgv3;
      const float si = 1.f / (1.f + expf(-iv));
      const float sf = 1.f / (1.f + expf(-fv));
      const float so = 1.f / (1.f + expf(-ov));
      c_reg = sf * c_reg + si * tanhf(gv);
      const float hnew = so * tanhf(c_reg);
      coh_store_f(&hseq[(size_t)(t * NB + bp) * NH + blockIdx.x * 8 + jp], hnew);
    }
    // ---- grid barrier ----
    if (t < NS - 1) {
      __syncthreads();
      if (tid == 0) {
        asm volatile("s_waitcnt vmcnt(0)" ::: "memory");
        __hip_atomic_fetch_add(&ctr[(blockIdx.x & 7) * 16], 1u,
                               __ATOMIC_RELAXED, __HIP_MEMORY_SCOPE_AGENT);
      }
      if (tid < 8) {
        const unsigned target = (unsigned)(t + 1) * (LBLK / 8);
        while (__hip_atomic_load(&ctr[tid * 16], __ATOMIC_RELAXED,
                                 __HIP_MEMORY_SCOPE_AGENT) < target)
          __builtin_amdgcn_s_sleep(1);
      }
      __syncthreads();
    }
  }
}

// ---------------------------------------------------------------------------
// preds[b*24+s] = dot(h1seq[s*32+b], Wout) + bout
// ---------------------------------------------------------------------------
__global__ __launch_bounds__(64) void head_kernel(
    const float* __restrict__ hseq1, const float* __restrict__ Wout,
    const float* __restrict__ bout, float* __restrict__ preds) {
  const int o = blockIdx.x;
  const int b = o / HOR_, s = o % HOR_;
  const int l = threadIdx.x;
  const float* h = hseq1 + (size_t)(s * NB + b) * NH;
  float acc = 0.f;
  #pragma unroll
  for (int k = l; k < NH; k += 64) acc += h[k] * Wout[k];
  #pragma unroll
  for (int m = 32; m; m >>= 1) acc += __shfl_xor(acc, m);
  if (l == 0) preds[o] = acc + bout[0];
}

// ---------------------------------------------------------------------------
extern "C" void kernel_launch(void* const* d_in, const int* in_sizes, int n_in,
                              void* d_out, int out_size, void* d_ws, size_t ws_size,
                              hipStream_t stream) {
  const float* z    = (const float*)d_in[0];
  const float* cond = (const float*)d_in[1];
  const float* encs = (const float*)d_in[2];
  const float* W1   = (const float*)d_in[4];
  const float* b1   = (const float*)d_in[5];
  const float* W2   = (const float*)d_in[6];
  const float* b2   = (const float*)d_in[7];
  const float* Wih0 = (const float*)d_in[8];
  const float* Whh0 = (const float*)d_in[9];
  const float* bih0 = (const float*)d_in[10];
  const float* bhh0 = (const float*)d_in[11];
  const float* Wih1 = (const float*)d_in[12];
  const float* Whh1 = (const float*)d_in[13];
  const float* bih1 = (const float*)d_in[14];
  const float* bhh1 = (const float*)d_in[15];
  const float* Wout = (const float*)d_in[16];
  const float* bout = (const float*)d_in[17];

  float* out     = (float*)d_out;
  float* preds   = out;
  float* enc_out = out + NB * HOR_;

  float* ws    = (float*)d_ws;
  float* xb    = ws + OFF_X;
  float* mean  = ws + OFF_MEAN;
  float* tmp   = ws + OFF_TMP;
  float* hseq0 = ws + OFF_HSEQ0;
  float* hseq1 = ws + OFF_HSEQ1;
  float* xg    = ws + OFF_XG;
  float* hzero = ws + OFF_HZERO;
  unsigned* ctr = (unsigned*)(ws + OFF_CTR);

  // allow >64KB dynamic LDS for the persistent kernel
  (void)hipFuncSetAttribute(reinterpret_cast<const void*>(lstm_persist),
                            hipFuncAttributeMaxDynamicSharedMemorySize,
                            160 * 1024);

  // 1. segment mean (filter and mean are linear and commute -> pool first)
  seg_mean_kernel<<<NSEG_, 192, 0, stream>>>(encs, mean);
  // 2. encoded = (mean @ W1^T + b1) @ W2^T + b2 -> straight into d_out (MFMA)
  gemm_mfma_nt<<<dim3(NH / 64, NSEG_ / 64), 256, 0, stream>>>(
      mean, W1, b1, nullptr, tmp, NSEG_, NH, NH);
  gemm_mfma_nt<<<dim3(NH / 64, NSEG_ / 64), 256, 0, stream>>>(
      tmp, W2, b2, nullptr, enc_out, NSEG_, NH, NH);
  // 3. x = concat(z, cond, encoded), time-major rows (s*32+b)
  build_x_kernel<<<(NSEG_ * NIN) / 256, 256, 0, stream>>>(z, cond, enc_out, xb);
  // 4. layer-0 input gates (biases folded in), K=816 (guarded chunks)
  gemm_mfma_nt<<<dim3(G4 / 64, NSEG_ / 64), 256, 0, stream>>>(
      xb, Wih0, bih0, bhh0, xg, NSEG_, G4, NIN);
  // 5. layer-0 recurrence (persistent MFMA kernel, h rotates through hseq0)
  hipMemsetAsync(hzero, 0, (size_t)(SZ_HZERO + 128) * sizeof(float), stream);
  lstm_persist<<<LBLK, LTHR, SMEM_BYTES, stream>>>(xg, Whh0, hzero, hseq0, ctr);
  // 6. layer-1 input gates (MFMA)
  gemm_mfma_nt<<<dim3(G4 / 64, NSEG_ / 64), 256, 0, stream>>>(
      hseq0, Wih1, bih1, bhh1, xg, NSEG_, G4, NH);
  // 7. layer-1 recurrence
  hipMemsetAsync(hzero, 0, (size_t)(SZ_HZERO + 128) * sizeof(float), stream);
  lstm_persist<<<LBLK, LTHR, SMEM_BYTES, stream>>>(xg, Whh1, hzero, hseq1, ctr);
  // 8. head
  head_kernel<<<NB * HOR_, 64, 0, stream>>>(hseq1, Wout, bout, preds);
}

// Round 11
// 791.731 us; speedup vs baseline: 10.8936x; 1.1246x over previous
//
#include <hip/hip_runtime.h>
#include <cstddef>

#define NB 32
#define NS 64
#define NH 768
#define NSEG_ (NB*NS)      // 2048
#define NIN 816
#define G4 3072
#define HOR_ 24
#define NL0 96             // layer-0 blocks
#define FBLK 192           // total fused blocks (96 L0 + 96 L1) <= 256 CUs
#define LTHR 512           // 8 waves/block

// MFMA fragment types (short-based bf16, compile-verified on gfx950)
typedef __attribute__((ext_vector_type(8))) short bf16x8;
typedef __attribute__((ext_vector_type(4))) float f32x4;
typedef __attribute__((ext_vector_type(8))) unsigned short u16x8;

// lstm dynamic-LDS partition: h as bf16 hi/lo [32][776] + partial-C [4][32][33]
#define HHP 776
#define SMEM_BYTES (2*32*HHP*2 + 4*32*33*4)   // 99328 + 16896 = 116224

// workspace offsets (floats)
#define OFF_X      0
#define SZ_X       (NSEG_*NIN)
#define OFF_MEAN   (OFF_X + SZ_X)
#define SZ_MEAN    (NSEG_*NH)
#define OFF_TMP    (OFF_MEAN + SZ_MEAN)
#define OFF_HSEQ0  (OFF_TMP + SZ_MEAN)
#define OFF_HSEQ1  (OFF_HSEQ0 + SZ_MEAN)
#define OFF_XG     (OFF_HSEQ1 + SZ_MEAN)
#define SZ_XG      (NSEG_*G4)
#define OFF_HZERO  (OFF_XG + SZ_XG)
#define SZ_HZERO   (NB*NH)
#define OFF_CTR    (OFF_HZERO + SZ_HZERO)   // 8 counters spread over 8 lines

// agent-scope write-through store (coherence point; proven r6)
__device__ __forceinline__ void coh_store_f(float* p, float v) {
  union { float f; unsigned u; } c; c.f = v;
  __hip_atomic_store((unsigned*)p, c.u, __ATOMIC_RELAXED,
                     __HIP_MEMORY_SCOPE_AGENT);
}

// split a float into bf16 hi + bf16 residual
__device__ __forceinline__ void split_bf16(float v, unsigned short& hi,
                                           unsigned short& lo) {
  const unsigned u = __float_as_uint(v);
  hi = (unsigned short)(u >> 16);
  const float rem = v - __uint_as_float(u & 0xffff0000u);
  lo = (unsigned short)(__float_as_uint(rem) >> 16);
}

// ---------------------------------------------------------------------------
// Segment mean: encs [65536,768] -> mean [2048,768]
// ---------------------------------------------------------------------------
__global__ __launch_bounds__(192) void seg_mean_kernel(
    const float* __restrict__ encs, float* __restrict__ mean) {
  const int s = blockIdx.x;
  const int t = threadIdx.x;
  const float4* base = (const float4*)(encs + (size_t)s * 32 * NH);
  float4 a = {0.f, 0.f, 0.f, 0.f};
  #pragma unroll 4
  for (int r = 0; r < 32; ++r) {
    float4 v = base[(size_t)r * (NH / 4) + t];
    a.x += v.x; a.y += v.y; a.z += v.z; a.w += v.w;
  }
  const float inv = 1.f / 32.f;
  float4 o = {a.x * inv, a.y * inv, a.z * inv, a.w * inv};
  ((float4*)mean)[(size_t)s * (NH / 4) + t] = o;
}

// ---------------------------------------------------------------------------
// Split-bf16 MFMA GEMM: C[M,N] = A[M,K] @ W[N,K]^T + bias1[n] + bias2[n]
// (round-10 proven: ~fp32 accuracy via hi.hi + hi.lo + lo.hi)
// ---------------------------------------------------------------------------
__global__ __launch_bounds__(256) void gemm_mfma_nt(
    const float* __restrict__ A, const float* __restrict__ W,
    const float* __restrict__ bias1, const float* __restrict__ bias2,
    float* __restrict__ C, int M, int N, int K) {
  __shared__ unsigned short Ahi[64 * 40];
  __shared__ unsigned short Alo[64 * 40];
  __shared__ unsigned short Whi[64 * 40];
  __shared__ unsigned short Wlo[64 * 40];
  const int tid = threadIdx.x;
  const int bm = blockIdx.y, bn = blockIdx.x;
  const int lane = tid & 63;
  const int wid  = tid >> 6;
  const int lm = lane & 15;
  const int lk = lane >> 4;
  const int srow = tid >> 2;             // staging row 0..63
  const int skc  = (tid & 3) * 8;        // staging k-chunk {0,8,16,24}

  const float* Ap = A + (size_t)(bm * 64 + srow) * K;
  const float* Wp = W + (size_t)(bn * 64 + srow) * K;

  f32x4 acc[4];
  #pragma unroll
  for (int nf = 0; nf < 4; ++nf) acc[nf] = (f32x4){0.f, 0.f, 0.f, 0.f};

  for (int k0 = 0; k0 < K; k0 += 32) {
    float va[8], vw[8];
    if (k0 + skc + 8 <= K) {
      float4 a0 = *(const float4*)(Ap + k0 + skc);
      float4 a1 = *(const float4*)(Ap + k0 + skc + 4);
      float4 w0 = *(const float4*)(Wp + k0 + skc);
      float4 w1 = *(const float4*)(Wp + k0 + skc + 4);
      va[0]=a0.x; va[1]=a0.y; va[2]=a0.z; va[3]=a0.w;
      va[4]=a1.x; va[5]=a1.y; va[6]=a1.z; va[7]=a1.w;
      vw[0]=w0.x; vw[1]=w0.y; vw[2]=w0.z; vw[3]=w0.w;
      vw[4]=w1.x; vw[5]=w1.y; vw[6]=w1.z; vw[7]=w1.w;
    } else {
      #pragma unroll
      for (int i = 0; i < 8; ++i) { va[i] = 0.f; vw[i] = 0.f; }
    }
    u16x8 AH, AL, WH, WL;
    #pragma unroll
    for (int i = 0; i < 8; ++i) {
      unsigned short h, l;
      split_bf16(va[i], h, l); AH[i] = h; AL[i] = l;
      split_bf16(vw[i], h, l); WH[i] = h; WL[i] = l;
    }
    __syncthreads();
    *(u16x8*)(&Ahi[srow * 40 + skc]) = AH;
    *(u16x8*)(&Alo[srow * 40 + skc]) = AL;
    *(u16x8*)(&Whi[srow * 40 + skc]) = WH;
    *(u16x8*)(&Wlo[srow * 40 + skc]) = WL;
    __syncthreads();
    bf16x8 ah = *(bf16x8*)(&Ahi[(wid * 16 + lm) * 40 + lk * 8]);
    bf16x8 al = *(bf16x8*)(&Alo[(wid * 16 + lm) * 40 + lk * 8]);
    #pragma unroll
    for (int nf = 0; nf < 4; ++nf) {
      bf16x8 bh = *(bf16x8*)(&Whi[(nf * 16 + lm) * 40 + lk * 8]);
      bf16x8 bl = *(bf16x8*)(&Wlo[(nf * 16 + lm) * 40 + lk * 8]);
      acc[nf] = __builtin_amdgcn_mfma_f32_16x16x32_bf16(ah, bh, acc[nf], 0, 0, 0);
      acc[nf] = __builtin_amdgcn_mfma_f32_16x16x32_bf16(ah, bl, acc[nf], 0, 0, 0);
      acc[nf] = __builtin_amdgcn_mfma_f32_16x16x32_bf16(al, bh, acc[nf], 0, 0, 0);
    }
  }
  #pragma unroll
  for (int nf = 0; nf < 4; ++nf) {
    const int gn = bn * 64 + nf * 16 + lm;
    float bb = 0.f;
    if (bias1) bb += bias1[gn];
    if (bias2) bb += bias2[gn];
    #pragma unroll
    for (int r4 = 0; r4 < 4; ++r4) {
      const int gm = bm * 64 + wid * 16 + lk * 4 + r4;
      C[(size_t)gm * N + gn] = acc[nf][r4] + bb;
    }
  }
}

// ---------------------------------------------------------------------------
// x[s*32+b][0:816] = concat(z[b,s], cond[b,s], encoded[b*64+s])
// ---------------------------------------------------------------------------
__global__ __launch_bounds__(256) void build_x_kernel(
    const float* __restrict__ z, const float* __restrict__ cond,
    const float* __restrict__ enc, float* __restrict__ x) {
  const int idx = blockIdx.x * 256 + threadIdx.x;
  const int r = idx / NIN, c = idx % NIN;
  const int s = r >> 5, b = r & 31;
  const int bs = b * NS + s;
  float v;
  if (c < 32)      v = z[bs * 32 + c];
  else if (c < 48) v = cond[bs * 16 + (c - 32)];
  else             v = enc[(size_t)bs * NH + (c - 48)];
  x[idx] = v;
}

// ---------------------------------------------------------------------------
// FUSED 2-layer persistent LSTM, software-pipelined across layers.
// 192 blocks x 512 threads: [0,96) = layer 0, [96,192) = layer 1.
// Epoch e: L0 computes step e (e<64) -- byte-identical math to the proven
// round-9 kernel; L1 computes step e-1 (e>=1) with
//   gates = Wih1 . h0(e-1)  [phase A, u-frags reloaded per K-step, L2-hot]
//         + Whh1 . h1(e-2)  [phase B, resident frags]  + biases.
// One shared barrier per epoch -> 64 barriers for BOTH layers, and the
// layer-1 input-gate GEMM disappears.  Coherence: every hseq row is written
// in one epoch and first-read one barrier later; row slabs are exact 128B
// line multiples (98304 B) so no stale-line hazard (r6-proven pattern).
// VGPR discipline (r8 lesson): only Whh frags resident (48 VGPR); Wih1
// frags transient (8 VGPR) -> peak ~110, below the 128 spill cliff.
// ---------------------------------------------------------------------------
__global__ __launch_bounds__(LTHR)
__attribute__((amdgpu_waves_per_eu(2, 2)))
void lstm_fused2(
    const float* __restrict__ xg0,   // [64*32][3072] layer-0 gates (biases folded)
    const float* __restrict__ Whh0,  // [3072][768]
    const float* __restrict__ Wih1,  // [3072][768]
    const float* __restrict__ Whh1,  // [3072][768]
    const float* __restrict__ bih1,  // [3072]
    const float* __restrict__ bhh1,  // [3072]
    const float* __restrict__ hzero, // [32][768] zeros
    float* hseq0,                    // [2048][768], row = t*32+b
    float* hseq1,                    // [2048][768], row = t*32+b
    unsigned* ctr) {                 // 8 counters at stride 16 u32, zeroed
  extern __shared__ __align__(16) unsigned short smem_us[];
  unsigned short* hh  = smem_us;                 // [32][HHP] bf16(h) hi
  unsigned short* hl  = smem_us + 32 * HHP;      // [32][HHP] bf16(h residual)
  float*          gsp = (float*)(smem_us + 2 * 32 * HHP);  // [4][32][33]

  const int tid  = threadIdx.x;
  const int lane = tid & 63;
  const int wid  = tid >> 6;
  const int mt   = wid >> 2;         // M-tile (rows mt*16 .. +16)
  const int kh   = wid & 3;          // K-quarter (k = kh*192 .. +192)
  const int lm   = lane & 15;
  const int lk   = lane >> 4;
  const bool isL1 = (blockIdx.x >= NL0);
  const int lblk  = isL1 ? (blockIdx.x - NL0) : blockIdx.x;

  // ---- resident A-frags: Whh (this layer), split hi/lo, loaded ONCE ----
  const int rloc = mt * 16 + lm;                       // gate-row 0..31
  const int grow = (rloc >> 3) * NH + lblk * 8 + (rloc & 7);
  const float* WhhP = isL1 ? Whh1 : Whh0;
  bf16x8 whi[6], wlo[6];
  #pragma unroll
  for (int s6 = 0; s6 < 6; ++s6) {
    const float* wp = WhhP + (size_t)grow * NH + kh * 192 + s6 * 32 + lk * 8;
    float4 a = *(const float4*)wp;
    float4 b = *(const float4*)(wp + 4);
    float vv[8] = {a.x, a.y, a.z, a.w, b.x, b.y, b.z, b.w};
    #pragma unroll
    for (int i = 0; i < 8; ++i) {
      unsigned short h, l;
      split_bf16(vv[i], h, l);
      whi[s6][i] = (short)h;
      wlo[s6][i] = (short)l;
    }
  }

  // pointwise mapping (tid < 256): cell (jp, bp), c kept in register
  const int jp = tid >> 5;           // 0..7
  const int bp = tid & 31;
  float c_reg = 0.f;
  // L1 pointwise biases (gate order i,f,g,o)
  float bi = 0.f, bf = 0.f, bg = 0.f, bo = 0.f;
  if (isL1 && tid < 256) {
    const int jj = lblk * 8 + jp;
    bi = bih1[0 * NH + jj] + bhh1[0 * NH + jj];
    bf = bih1[1 * NH + jj] + bhh1[1 * NH + jj];
    bg = bih1[2 * NH + jj] + bhh1[2 * NH + jj];
    bo = bih1[3 * NH + jj] + bhh1[3 * NH + jj];
  }

  // staging mapping: batch = tid>>4, chunk column = tid&15
  const int sb  = tid >> 4;          // 0..31
  const int sch = tid & 15;          // 0..15

  for (int e = 0; e <= NS; ++e) {
    if (!isL1) {
      // =============== layer 0, step t = e ===============
      if (e < NS) {
        const int t = e;
        const float* hRead = (t == 0) ? hzero : hseq0 + (size_t)(t - 1) * NB * NH;
        float xgv0 = 0.f, xgv1 = 0.f, xgv2 = 0.f, xgv3 = 0.f;
        if (tid < 256) {
          const float* xr = xg0 + (size_t)(t * NB + bp) * G4 + (lblk * 8 + jp);
          xgv0 = xr[0]; xgv1 = xr[NH]; xgv2 = xr[2 * NH]; xgv3 = xr[3 * NH];
        }
        #pragma unroll
        for (int it = 0; it < 6; ++it) {
          const int k0 = (sch + it * 16) * 8;
          float4 v0 = *(const float4*)(hRead + (size_t)sb * NH + k0);
          float4 v1 = *(const float4*)(hRead + (size_t)sb * NH + k0 + 4);
          float vv[8] = {v0.x, v0.y, v0.z, v0.w, v1.x, v1.y, v1.z, v1.w};
          u16x8 HI, LO;
          #pragma unroll
          for (int i = 0; i < 8; ++i) {
            unsigned short h, l;
            split_bf16(vv[i], h, l);
            HI[i] = h; LO[i] = l;
          }
          *(u16x8*)(&hh[sb * HHP + k0]) = HI;
          *(u16x8*)(&hl[sb * HHP + k0]) = LO;
        }
        __syncthreads();
        f32x4 acc0 = {0.f, 0.f, 0.f, 0.f};
        f32x4 acc1 = {0.f, 0.f, 0.f, 0.f};
        #pragma unroll
        for (int s6 = 0; s6 < 6; ++s6) {
          const int kb = kh * 192 + s6 * 32 + lk * 8;
          bf16x8 bh0 = *(bf16x8*)(&hh[lm * HHP + kb]);
          bf16x8 bl0 = *(bf16x8*)(&hl[lm * HHP + kb]);
          bf16x8 bh1 = *(bf16x8*)(&hh[(16 + lm) * HHP + kb]);
          bf16x8 bl1 = *(bf16x8*)(&hl[(16 + lm) * HHP + kb]);
          acc0 = __builtin_amdgcn_mfma_f32_16x16x32_bf16(whi[s6], bh0, acc0, 0, 0, 0);
          acc0 = __builtin_amdgcn_mfma_f32_16x16x32_bf16(whi[s6], bl0, acc0, 0, 0, 0);
          acc0 = __builtin_amdgcn_mfma_f32_16x16x32_bf16(wlo[s6], bh0, acc0, 0, 0, 0);
          acc1 = __builtin_amdgcn_mfma_f32_16x16x32_bf16(whi[s6], bh1, acc1, 0, 0, 0);
          acc1 = __builtin_amdgcn_mfma_f32_16x16x32_bf16(whi[s6], bl1, acc1, 0, 0, 0);
          acc1 = __builtin_amdgcn_mfma_f32_16x16x32_bf16(wlo[s6], bh1, acc1, 0, 0, 0);
        }
        #pragma unroll
        for (int r4 = 0; r4 < 4; ++r4) {
          gsp[kh * 1056 + (mt * 16 + lk * 4 + r4) * 33 + lm]      = acc0[r4];
          gsp[kh * 1056 + (mt * 16 + lk * 4 + r4) * 33 + 16 + lm] = acc1[r4];
        }
        __syncthreads();
        if (tid < 256) {
          float sum[4];
          #pragma unroll
          for (int g = 0; g < 4; ++g) {
            const int row = g * 8 + jp;
            sum[g] = gsp[0 * 1056 + row * 33 + bp] + gsp[1 * 1056 + row * 33 + bp] +
                     gsp[2 * 1056 + row * 33 + bp] + gsp[3 * 1056 + row * 33 + bp];
          }
          const float iv = sum[0] + xgv0;
          const float fv = sum[1] + xgv1;
          const float gv = sum[2] + xgv2;
          const float ov = sum[3] + xgv3;
          const float si = 1.f / (1.f + expf(-iv));
          const float sf = 1.f / (1.f + expf(-fv));
          const float so = 1.f / (1.f + expf(-ov));
          c_reg = sf * c_reg + si * tanhf(gv);
          const float hnew = so * tanhf(c_reg);
          coh_store_f(&hseq0[(size_t)(t * NB + bp) * NH + lblk * 8 + jp], hnew);
        }
      }
    } else {
      // =============== layer 1, step t = e - 1 ===============
      if (e >= 1) {
        const int t = e - 1;
        const float* h0r = hseq0 + (size_t)t * NB * NH;
        const float* h1r = (t == 0) ? hzero : hseq1 + (size_t)(t - 1) * NB * NH;
        // ---- phase A: stage h0, acc = Wih1 . h0(t) (u-frags reloaded) ----
        #pragma unroll
        for (int it = 0; it < 6; ++it) {
          const int k0 = (sch + it * 16) * 8;
          float4 v0 = *(const float4*)(h0r + (size_t)sb * NH + k0);
          float4 v1 = *(const float4*)(h0r + (size_t)sb * NH + k0 + 4);
          float vv[8] = {v0.x, v0.y, v0.z, v0.w, v1.x, v1.y, v1.z, v1.w};
          u16x8 HI, LO;
          #pragma unroll
          for (int i = 0; i < 8; ++i) {
            unsigned short h, l;
            split_bf16(vv[i], h, l);
            HI[i] = h; LO[i] = l;
          }
          *(u16x8*)(&hh[sb * HHP + k0]) = HI;
          *(u16x8*)(&hl[sb * HHP + k0]) = LO;
        }
        __syncthreads();
        f32x4 acc0 = {0.f, 0.f, 0.f, 0.f};
        f32x4 acc1 = {0.f, 0.f, 0.f, 0.f};
        #pragma unroll
        for (int s6 = 0; s6 < 6; ++s6) {
          // transient u-frags (same address every step -> L2-hot)
          const float* up = Wih1 + (size_t)grow * NH + kh * 192 + s6 * 32 + lk * 8;
          float4 ua = *(const float4*)up;
          float4 ub = *(const float4*)(up + 4);
          float uv[8] = {ua.x, ua.y, ua.z, ua.w, ub.x, ub.y, ub.z, ub.w};
          bf16x8 uh, ul;
          #pragma unroll
          for (int i = 0; i < 8; ++i) {
            unsigned short h, l;
            split_bf16(uv[i], h, l);
            uh[i] = (short)h;
            ul[i] = (short)l;
          }
          const int kb = kh * 192 + s6 * 32 + lk * 8;
          bf16x8 bh0 = *(bf16x8*)(&hh[lm * HHP + kb]);
          bf16x8 bl0 = *(bf16x8*)(&hl[lm * HHP + kb]);
          bf16x8 bh1 = *(bf16x8*)(&hh[(16 + lm) * HHP + kb]);
          bf16x8 bl1 = *(bf16x8*)(&hl[(16 + lm) * HHP + kb]);
          acc0 = __builtin_amdgcn_mfma_f32_16x16x32_bf16(uh, bh0, acc0, 0, 0, 0);
          acc0 = __builtin_amdgcn_mfma_f32_16x16x32_bf16(uh, bl0, acc0, 0, 0, 0);
          acc0 = __builtin_amdgcn_mfma_f32_16x16x32_bf16(ul, bh0, acc0, 0, 0, 0);
          acc1 = __builtin_amdgcn_mfma_f32_16x16x32_bf16(uh, bh1, acc1, 0, 0, 0);
          acc1 = __builtin_amdgcn_mfma_f32_16x16x32_bf16(uh, bl1, acc1, 0, 0, 0);
          acc1 = __builtin_amdgcn_mfma_f32_16x16x32_bf16(ul, bh1, acc1, 0, 0, 0);
        }
        __syncthreads();   // phase-A frag reads done; h_lds safe to restage
        // ---- phase B: stage h1, acc += Whh1 . h1(t-1) (resident frags) ----
        #pragma unroll
        for (int it = 0; it < 6; ++it) {
          const int k0 = (sch + it * 16) * 8;
          float4 v0 = *(const float4*)(h1r + (size_t)sb * NH + k0);
          float4 v1 = *(const float4*)(h1r + (size_t)sb * NH + k0 + 4);
          float vv[8] = {v0.x, v0.y, v0.z, v0.w, v1.x, v1.y, v1.z, v1.w};
          u16x8 HI, LO;
          #pragma unroll
          for (int i = 0; i < 8; ++i) {
            unsigned short h, l;
            split_bf16(vv[i], h, l);
            HI[i] = h; LO[i] = l;
          }
          *(u16x8*)(&hh[sb * HHP + k0]) = HI;
          *(u16x8*)(&hl[sb * HHP + k0]) = LO;
        }
        __syncthreads();
        #pragma unroll
        for (int s6 = 0; s6 < 6; ++s6) {
          const int kb = kh * 192 + s6 * 32 + lk * 8;
          bf16x8 bh0 = *(bf16x8*)(&hh[lm * HHP + kb]);
          bf16x8 bl0 = *(bf16x8*)(&hl[lm * HHP + kb]);
          bf16x8 bh1 = *(bf16x8*)(&hh[(16 + lm) * HHP + kb]);
          bf16x8 bl1 = *(bf16x8*)(&hl[(16 + lm) * HHP + kb]);
          acc0 = __builtin_amdgcn_mfma_f32_16x16x32_bf16(whi[s6], bh0, acc0, 0, 0, 0);
          acc0 = __builtin_amdgcn_mfma_f32_16x16x32_bf16(whi[s6], bl0, acc0, 0, 0, 0);
          acc0 = __builtin_amdgcn_mfma_f32_16x16x32_bf16(wlo[s6], bh0, acc0, 0, 0, 0);
          acc1 = __builtin_amdgcn_mfma_f32_16x16x32_bf16(whi[s6], bh1, acc1, 0, 0, 0);
          acc1 = __builtin_amdgcn_mfma_f32_16x16x32_bf16(whi[s6], bl1, acc1, 0, 0, 0);
          acc1 = __builtin_amdgcn_mfma_f32_16x16x32_bf16(wlo[s6], bh1, acc1, 0, 0, 0);
        }
        #pragma unroll
        for (int r4 = 0; r4 < 4; ++r4) {
          gsp[kh * 1056 + (mt * 16 + lk * 4 + r4) * 33 + lm]      = acc0[r4];
          gsp[kh * 1056 + (mt * 16 + lk * 4 + r4) * 33 + 16 + lm] = acc1[r4];
        }
        __syncthreads();
        if (tid < 256) {
          float sum[4];
          #pragma unroll
          for (int g = 0; g < 4; ++g) {
            const int row = g * 8 + jp;
            sum[g] = gsp[0 * 1056 + row * 33 + bp] + gsp[1 * 1056 + row * 33 + bp] +
                     gsp[2 * 1056 + row * 33 + bp] + gsp[3 * 1056 + row * 33 + bp];
          }
          const float iv = sum[0] + bi;
          const float fv = sum[1] + bf;
          const float gv = sum[2] + bg;
          const float ov = sum[3] + bo;
          const float si = 1.f / (1.f + expf(-iv));
          const float sf = 1.f / (1.f + expf(-fv));
          const float so = 1.f / (1.f + expf(-ov));
          c_reg = sf * c_reg + si * tanhf(gv);
          const float hnew = so * tanhf(c_reg);
          coh_store_f(&hseq1[(size_t)(t * NB + bp) * NH + lblk * 8 + jp], hnew);
        }
      }
    }
    // ---- shared grid barrier (epochs 0..63; epoch 64 ends the kernel) ----
    if (e < NS) {
      __syncthreads();
      if (tid == 0) {
        asm volatile("s_waitcnt vmcnt(0)" ::: "memory");
        __hip_atomic_fetch_add(&ctr[(blockIdx.x & 7) * 16], 1u,
                               __ATOMIC_RELAXED, __HIP_MEMORY_SCOPE_AGENT);
      }
      if (tid < 8) {
        const unsigned target = (unsigned)(e + 1) * (FBLK / 8);
        while (__hip_atomic_load(&ctr[tid * 16], __ATOMIC_RELAXED,
                                 __HIP_MEMORY_SCOPE_AGENT) < target)
          __builtin_amdgcn_s_sleep(1);
      }
      __syncthreads();
    }
  }
}

// ---------------------------------------------------------------------------
// preds[b*24+s] = dot(h1seq[s*32+b], Wout) + bout
// ---------------------------------------------------------------------------
__global__ __launch_bounds__(64) void head_kernel(
    const float* __restrict__ hseq1, const float* __restrict__ Wout,
    const float* __restrict__ bout, float* __restrict__ preds) {
  const int o = blockIdx.x;
  const int b = o / HOR_, s = o % HOR_;
  const int l = threadIdx.x;
  const float* h = hseq1 + (size_t)(s * NB + b) * NH;
  float acc = 0.f;
  #pragma unroll
  for (int k = l; k < NH; k += 64) acc += h[k] * Wout[k];
  #pragma unroll
  for (int m = 32; m; m >>= 1) acc += __shfl_xor(acc, m);
  if (l == 0) preds[o] = acc + bout[0];
}

// ---------------------------------------------------------------------------
extern "C" void kernel_launch(void* const* d_in, const int* in_sizes, int n_in,
                              void* d_out, int out_size, void* d_ws, size_t ws_size,
                              hipStream_t stream) {
  const float* z    = (const float*)d_in[0];
  const float* cond = (const float*)d_in[1];
  const float* encs = (const float*)d_in[2];
  const float* W1   = (const float*)d_in[4];
  const float* b1   = (const float*)d_in[5];
  const float* W2   = (const float*)d_in[6];
  const float* b2   = (const float*)d_in[7];
  const float* Wih0 = (const float*)d_in[8];
  const float* Whh0 = (const float*)d_in[9];
  const float* bih0 = (const float*)d_in[10];
  const float* bhh0 = (const float*)d_in[11];
  const float* Wih1 = (const float*)d_in[12];
  const float* Whh1 = (const float*)d_in[13];
  const float* bih1 = (const float*)d_in[14];
  const float* bhh1 = (const float*)d_in[15];
  const float* Wout = (const float*)d_in[16];
  const float* bout = (const float*)d_in[17];

  float* out     = (float*)d_out;
  float* preds   = out;
  float* enc_out = out + NB * HOR_;

  float* ws    = (float*)d_ws;
  float* xb    = ws + OFF_X;
  float* mean  = ws + OFF_MEAN;
  float* tmp   = ws + OFF_TMP;
  float* hseq0 = ws + OFF_HSEQ0;
  float* hseq1 = ws + OFF_HSEQ1;
  float* xg    = ws + OFF_XG;
  float* hzero = ws + OFF_HZERO;
  unsigned* ctr = (unsigned*)(ws + OFF_CTR);

  // allow >64KB dynamic LDS for the persistent kernel
  (void)hipFuncSetAttribute(reinterpret_cast<const void*>(lstm_fused2),
                            hipFuncAttributeMaxDynamicSharedMemorySize,
                            160 * 1024);

  // 1. segment mean (filter and mean are linear and commute -> pool first)
  seg_mean_kernel<<<NSEG_, 192, 0, stream>>>(encs, mean);
  // 2. encoded = (mean @ W1^T + b1) @ W2^T + b2 -> straight into d_out (MFMA)
  gemm_mfma_nt<<<dim3(NH / 64, NSEG_ / 64), 256, 0, stream>>>(
      mean, W1, b1, nullptr, tmp, NSEG_, NH, NH);
  gemm_mfma_nt<<<dim3(NH / 64, NSEG_ / 64), 256, 0, stream>>>(
      tmp, W2, b2, nullptr, enc_out, NSEG_, NH, NH);
  // 3. x = concat(z, cond, encoded), time-major rows (s*32+b)
  build_x_kernel<<<(NSEG_ * NIN) / 256, 256, 0, stream>>>(z, cond, enc_out, xb);
  // 4. layer-0 input gates (biases folded in), K=816 (guarded chunks)
  gemm_mfma_nt<<<dim3(G4 / 64, NSEG_ / 64), 256, 0, stream>>>(
      xb, Wih0, bih0, bhh0, xg, NSEG_, G4, NIN);
  // 5. fused, pipelined 2-layer recurrence (layer-1 xg GEMM folded in)
  hipMemsetAsync(hzero, 0, (size_t)(SZ_HZERO + 128) * sizeof(float), stream);
  lstm_fused2<<<FBLK, LTHR, SMEM_BYTES, stream>>>(
      xg, Whh0, Wih1, Whh1, bih1, bhh1, hzero, hseq0, hseq1, ctr);
  // 6. head
  head_kernel<<<NB * HOR_, 64, 0, stream>>>(hseq1, Wout, bout, preds);
}

// Round 12
// 728.623 us; speedup vs baseline: 11.8371x; 1.0866x over previous
//
#include <hip/hip_runtime.h>
#include <cstddef>

#define NB 32
#define NS 64
#define NH 768
#define NSEG_ (NB*NS)      // 2048
#define NIN 816
#define G4 3072
#define HOR_ 24
#define FBLK 192           // merged blocks: each owns 4 j of L0 + 4 j of L1
#define LTHR 512           // 8 waves/block
#define NCTR 16            // barrier counter lines

// MFMA fragment types (short-based bf16, compile-verified on gfx950)
typedef __attribute__((ext_vector_type(8))) short bf16x8;
typedef __attribute__((ext_vector_type(4))) float f32x4;
typedef __attribute__((ext_vector_type(8))) unsigned short u16x8;

// lstm dynamic-LDS: h bf16 hi/lo [32][776] + partial-C [8][16][33]
#define HHP 776
#define SMEM_BYTES (2*32*HHP*2 + 8*528*4)   // 99328 + 16896 = 116224

// workspace offsets (floats / u32s)
#define OFF_X      0
#define SZ_X       (NSEG_*NIN)
#define OFF_MEAN   (OFF_X + SZ_X)
#define SZ_MEAN    (NSEG_*NH)
#define OFF_TMP    (OFF_MEAN + SZ_MEAN)
#define OFF_H0PK   (OFF_TMP + SZ_MEAN)      // [2048][768] packed bf16 hi|lo
#define OFF_H1PK   (OFF_H0PK + SZ_MEAN)
#define OFF_XG     (OFF_H1PK + SZ_MEAN)
#define SZ_XG      (NSEG_*G4)
#define OFF_HZERO  (OFF_XG + SZ_XG)
#define SZ_HZERO   (NB*NH)
#define OFF_CTR    (OFF_HZERO + SZ_HZERO)   // 16 counters spread over 16 lines

// agent-scope write-through store (coherence point; proven r6)
__device__ __forceinline__ void coh_store_u32(unsigned* p, unsigned v) {
  __hip_atomic_store(p, v, __ATOMIC_RELAXED, __HIP_MEMORY_SCOPE_AGENT);
}

// split a float into bf16 hi + bf16 residual
__device__ __forceinline__ void split_bf16(float v, unsigned short& hi,
                                           unsigned short& lo) {
  const unsigned u = __float_as_uint(v);
  hi = (unsigned short)(u >> 16);
  const float rem = v - __uint_as_float(u & 0xffff0000u);
  lo = (unsigned short)(__float_as_uint(rem) >> 16);
}

// stage packed-bf16 h [32][768] u32 -> hh/hl LDS planes (2 shifts per elem)
__device__ __forceinline__ void stage_hpk(const unsigned* __restrict__ src,
                                          unsigned short* hh,
                                          unsigned short* hl,
                                          int sb, int sch) {
  #pragma unroll
  for (int it = 0; it < 6; ++it) {
    const int k0 = (sch + it * 16) * 8;
    uint4 wa = *(const uint4*)(src + (size_t)sb * NH + k0);
    uint4 wb = *(const uint4*)(src + (size_t)sb * NH + k0 + 4);
    unsigned ww[8] = {wa.x, wa.y, wa.z, wa.w, wb.x, wb.y, wb.z, wb.w};
    u16x8 HI, LO;
    #pragma unroll
    for (int i = 0; i < 8; ++i) {
      HI[i] = (unsigned short)(ww[i] >> 16);
      LO[i] = (unsigned short)(ww[i]);
    }
    *(u16x8*)(&hh[sb * HHP + k0]) = HI;
    *(u16x8*)(&hl[sb * HHP + k0]) = LO;
  }
}

// ---------------------------------------------------------------------------
// Segment mean: encs [65536,768] -> mean [2048,768]
// ---------------------------------------------------------------------------
__global__ __launch_bounds__(192) void seg_mean_kernel(
    const float* __restrict__ encs, float* __restrict__ mean) {
  const int s = blockIdx.x;
  const int t = threadIdx.x;
  const float4* base = (const float4*)(encs + (size_t)s * 32 * NH);
  float4 a = {0.f, 0.f, 0.f, 0.f};
  #pragma unroll 4
  for (int r = 0; r < 32; ++r) {
    float4 v = base[(size_t)r * (NH / 4) + t];
    a.x += v.x; a.y += v.y; a.z += v.z; a.w += v.w;
  }
  const float inv = 1.f / 32.f;
  float4 o = {a.x * inv, a.y * inv, a.z * inv, a.w * inv};
  ((float4*)mean)[(size_t)s * (NH / 4) + t] = o;
}

// ---------------------------------------------------------------------------
// Split-bf16 MFMA GEMM: C[M,N] = A[M,K] @ W[N,K]^T + bias1[n] + bias2[n]
// (round-10 proven: ~fp32 accuracy via hi.hi + hi.lo + lo.hi)
// ---------------------------------------------------------------------------
__global__ __launch_bounds__(256) void gemm_mfma_nt(
    const float* __restrict__ A, const float* __restrict__ W,
    const float* __restrict__ bias1, const float* __restrict__ bias2,
    float* __restrict__ C, int M, int N, int K) {
  __shared__ unsigned short Ahi[64 * 40];
  __shared__ unsigned short Alo[64 * 40];
  __shared__ unsigned short Whi[64 * 40];
  __shared__ unsigned short Wlo[64 * 40];
  const int tid = threadIdx.x;
  const int bm = blockIdx.y, bn = blockIdx.x;
  const int lane = tid & 63;
  const int wid  = tid >> 6;
  const int lm = lane & 15;
  const int lk = lane >> 4;
  const int srow = tid >> 2;
  const int skc  = (tid & 3) * 8;

  const float* Ap = A + (size_t)(bm * 64 + srow) * K;
  const float* Wp = W + (size_t)(bn * 64 + srow) * K;

  f32x4 acc[4];
  #pragma unroll
  for (int nf = 0; nf < 4; ++nf) acc[nf] = (f32x4){0.f, 0.f, 0.f, 0.f};

  for (int k0 = 0; k0 < K; k0 += 32) {
    float va[8], vw[8];
    if (k0 + skc + 8 <= K) {
      float4 a0 = *(const float4*)(Ap + k0 + skc);
      float4 a1 = *(const float4*)(Ap + k0 + skc + 4);
      float4 w0 = *(const float4*)(Wp + k0 + skc);
      float4 w1 = *(const float4*)(Wp + k0 + skc + 4);
      va[0]=a0.x; va[1]=a0.y; va[2]=a0.z; va[3]=a0.w;
      va[4]=a1.x; va[5]=a1.y; va[6]=a1.z; va[7]=a1.w;
      vw[0]=w0.x; vw[1]=w0.y; vw[2]=w0.z; vw[3]=w0.w;
      vw[4]=w1.x; vw[5]=w1.y; vw[6]=w1.z; vw[7]=w1.w;
    } else {
      #pragma unroll
      for (int i = 0; i < 8; ++i) { va[i] = 0.f; vw[i] = 0.f; }
    }
    u16x8 AH, AL, WH, WL;
    #pragma unroll
    for (int i = 0; i < 8; ++i) {
      unsigned short h, l;
      split_bf16(va[i], h, l); AH[i] = h; AL[i] = l;
      split_bf16(vw[i], h, l); WH[i] = h; WL[i] = l;
    }
    __syncthreads();
    *(u16x8*)(&Ahi[srow * 40 + skc]) = AH;
    *(u16x8*)(&Alo[srow * 40 + skc]) = AL;
    *(u16x8*)(&Whi[srow * 40 + skc]) = WH;
    *(u16x8*)(&Wlo[srow * 40 + skc]) = WL;
    __syncthreads();
    bf16x8 ah = *(bf16x8*)(&Ahi[(wid * 16 + lm) * 40 + lk * 8]);
    bf16x8 al = *(bf16x8*)(&Alo[(wid * 16 + lm) * 40 + lk * 8]);
    #pragma unroll
    for (int nf = 0; nf < 4; ++nf) {
      bf16x8 bh = *(bf16x8*)(&Whi[(nf * 16 + lm) * 40 + lk * 8]);
      bf16x8 bl = *(bf16x8*)(&Wlo[(nf * 16 + lm) * 40 + lk * 8]);
      acc[nf] = __builtin_amdgcn_mfma_f32_16x16x32_bf16(ah, bh, acc[nf], 0, 0, 0);
      acc[nf] = __builtin_amdgcn_mfma_f32_16x16x32_bf16(ah, bl, acc[nf], 0, 0, 0);
      acc[nf] = __builtin_amdgcn_mfma_f32_16x16x32_bf16(al, bh, acc[nf], 0, 0, 0);
    }
  }
  #pragma unroll
  for (int nf = 0; nf < 4; ++nf) {
    const int gn = bn * 64 + nf * 16 + lm;
    float bb = 0.f;
    if (bias1) bb += bias1[gn];
    if (bias2) bb += bias2[gn];
    #pragma unroll
    for (int r4 = 0; r4 < 4; ++r4) {
      const int gm = bm * 64 + wid * 16 + lk * 4 + r4;
      C[(size_t)gm * N + gn] = acc[nf][r4] + bb;
    }
  }
}

// ---------------------------------------------------------------------------
// x[s*32+b][0:816] = concat(z[b,s], cond[b,s], encoded[b*64+s])
// ---------------------------------------------------------------------------
__global__ __launch_bounds__(256) void build_x_kernel(
    const float* __restrict__ z, const float* __restrict__ cond,
    const float* __restrict__ enc, float* __restrict__ x) {
  const int idx = blockIdx.x * 256 + threadIdx.x;
  const int r = idx / NIN, c = idx % NIN;
  const int s = r >> 5, b = r & 31;
  const int bs = b * NS + s;
  float v;
  if (c < 32)      v = z[bs * 32 + c];
  else if (c < 48) v = cond[bs * 16 + (c - 32)];
  else             v = enc[(size_t)bs * NH + (c - 48)];
  x[idx] = v;
}

// ---------------------------------------------------------------------------
// MERGED 2-layer persistent LSTM.  192 blocks x 512 threads; each block owns
// 4 hidden units of layer 0 AND 4 of layer 1 (16 gate rows each, M=16).
// Waves 0-3 (kh quarters): L0 product Whh0.h0 -> gsp[0..3].
// Waves 4-7: L1 phase A Wih1.h0 (acc in regs; u-frags reloaded per K-step,
// L2-hot) then phase B + Whh1.h1 -> gsp[4..7].  Resident Whh frags live in
// the SAME 48 VGPRs (wave-uniform layer select) -- r8 spill cliff avoided.
// h exchanged as PACKED bf16 (hi<<16|lo) u32: producers split once, stagers
// unpack with 2 shifts/elem (was ~6 float ops) -- MFMA sees bit-identical
// hi/lo, numerics unchanged.  One staging of h0 serves both layers -> 2
// stagings/epoch instead of 3, perfectly balanced blocks.
// Epoch e: L0 step e (e<64); L1 step e-1 (e>=1).  64 shared barriers.
// Coherence: write-through stores + first-touch cached reads (r6-proven).
// ---------------------------------------------------------------------------
__global__ __launch_bounds__(LTHR)
__attribute__((amdgpu_waves_per_eu(2, 2)))
void lstm_merged(
    const float* __restrict__ xg0,   // [64*32][3072] layer-0 gates (biases folded)
    const float* __restrict__ Whh0,  // [3072][768]
    const float* __restrict__ Wih1,  // [3072][768]
    const float* __restrict__ Whh1,  // [3072][768]
    const float* __restrict__ bih1,  // [3072]
    const float* __restrict__ bhh1,  // [3072]
    const unsigned* __restrict__ hzero, // [32][768] packed zeros
    unsigned* h0pk,                  // [2048][768] packed bf16, row = t*32+b
    unsigned* h1pk,                  // [2048][768] packed bf16
    unsigned* ctr) {                 // 16 counters at stride 16 u32, zeroed
  extern __shared__ __align__(16) unsigned short smem_us[];
  unsigned short* hh  = smem_us;                 // [32][HHP] bf16 hi
  unsigned short* hl  = smem_us + 32 * HHP;      // [32][HHP] bf16 lo
  float*          gsp = (float*)(smem_us + 2 * 32 * HHP);  // [8][16][33]

  const int tid  = threadIdx.x;
  const int lane = tid & 63;
  const int wid  = tid >> 6;          // 0..7
  const bool wL1 = (wid >= 4);        // waves 4-7 compute layer-1 products
  const int kh   = wid & 3;           // K-quarter (k = kh*192 .. +192)
  const int lm   = lane & 15;
  const int lk   = lane >> 4;
  const int lblk = blockIdx.x;

  // resident Whh frags (L0 or L1 depending on wave -- same registers)
  const int grow = (lm >> 2) * NH + lblk * 4 + (lm & 3);  // gate-row (M=16)
  const float* WhhP = wL1 ? Whh1 : Whh0;
  bf16x8 whi[6], wlo[6];
  #pragma unroll
  for (int s6 = 0; s6 < 6; ++s6) {
    const float* wp = WhhP + (size_t)grow * NH + kh * 192 + s6 * 32 + lk * 8;
    float4 a = *(const float4*)wp;
    float4 b = *(const float4*)(wp + 4);
    float vv[8] = {a.x, a.y, a.z, a.w, b.x, b.y, b.z, b.w};
    #pragma unroll
    for (int i = 0; i < 8; ++i) {
      unsigned short h, l;
      split_bf16(vv[i], h, l);
      whi[s6][i] = (short)h;
      wlo[s6][i] = (short)l;
    }
  }

  // pointwise (tid<256): jp = tid>>5 in 0..7; jp<4 -> L0 cell, else L1
  const int jp = tid >> 5;
  const int bp = tid & 31;
  const bool pwL1 = (jp >= 4);
  const int jloc = jp & 3;
  float c_reg = 0.f;
  float bi = 0.f, bf_ = 0.f, bg = 0.f, bo = 0.f;
  if (tid < 256 && pwL1) {
    const int jj = lblk * 4 + jloc;
    bi  = bih1[0 * NH + jj] + bhh1[0 * NH + jj];
    bf_ = bih1[1 * NH + jj] + bhh1[1 * NH + jj];
    bg  = bih1[2 * NH + jj] + bhh1[2 * NH + jj];
    bo  = bih1[3 * NH + jj] + bhh1[3 * NH + jj];
  }
  const int sb  = tid >> 4;          // staging batch 0..31
  const int sch = tid & 15;          // staging chunk

  for (int e = 0; e <= NS; ++e) {
    const unsigned* h0r = (e == 0) ? hzero : h0pk + (size_t)(e - 1) * NB * NH;
    const unsigned* h1r = (e <= 1) ? hzero : h1pk + (size_t)(e - 2) * NB * NH;
    // L0 xg prefetch (hides under staging/MFMA)
    float xgv0 = 0.f, xgv1 = 0.f, xgv2 = 0.f, xgv3 = 0.f;
    if (tid < 256 && !pwL1 && e < NS) {
      const float* xr = xg0 + (size_t)(e * NB + bp) * G4 + (lblk * 4 + jloc);
      xgv0 = xr[0]; xgv1 = xr[NH]; xgv2 = xr[2 * NH]; xgv3 = xr[3 * NH];
    }
    // ---- stage h0(e-1): consumed by BOTH the L0 product and L1 phase A ----
    stage_hpk(h0r, hh, hl, sb, sch);
    __syncthreads();
    f32x4 acc0 = {0.f, 0.f, 0.f, 0.f};
    f32x4 acc1 = {0.f, 0.f, 0.f, 0.f};
    if (!wL1) {
      // L0: gates = Whh0 . h0(e-1)
      #pragma unroll
      for (int s6 = 0; s6 < 6; ++s6) {
        const int kb = kh * 192 + s6 * 32 + lk * 8;
        bf16x8 bh0 = *(bf16x8*)(&hh[lm * HHP + kb]);
        bf16x8 bl0 = *(bf16x8*)(&hl[lm * HHP + kb]);
        bf16x8 bh1 = *(bf16x8*)(&hh[(16 + lm) * HHP + kb]);
        bf16x8 bl1 = *(bf16x8*)(&hl[(16 + lm) * HHP + kb]);
        acc0 = __builtin_amdgcn_mfma_f32_16x16x32_bf16(whi[s6], bh0, acc0, 0, 0, 0);
        acc0 = __builtin_amdgcn_mfma_f32_16x16x32_bf16(whi[s6], bl0, acc0, 0, 0, 0);
        acc0 = __builtin_amdgcn_mfma_f32_16x16x32_bf16(wlo[s6], bh0, acc0, 0, 0, 0);
        acc1 = __builtin_amdgcn_mfma_f32_16x16x32_bf16(whi[s6], bh1, acc1, 0, 0, 0);
        acc1 = __builtin_amdgcn_mfma_f32_16x16x32_bf16(whi[s6], bl1, acc1, 0, 0, 0);
        acc1 = __builtin_amdgcn_mfma_f32_16x16x32_bf16(wlo[s6], bh1, acc1, 0, 0, 0);
      }
      #pragma unroll
      for (int r4 = 0; r4 < 4; ++r4) {
        gsp[wid * 528 + (lk * 4 + r4) * 33 + lm]      = acc0[r4];
        gsp[wid * 528 + (lk * 4 + r4) * 33 + 16 + lm] = acc1[r4];
      }
    } else {
      // L1 phase A: acc = Wih1 . h0(e-1)  (u-frags reloaded, L2-hot)
      #pragma unroll
      for (int s6 = 0; s6 < 6; ++s6) {
        const float* up = Wih1 + (size_t)grow * NH + kh * 192 + s6 * 32 + lk * 8;
        float4 ua = *(const float4*)up;
        float4 ub = *(const float4*)(up + 4);
        float uv[8] = {ua.x, ua.y, ua.z, ua.w, ub.x, ub.y, ub.z, ub.w};
        bf16x8 uh, ul;
        #pragma unroll
        for (int i = 0; i < 8; ++i) {
          unsigned short h, l;
          split_bf16(uv[i], h, l);
          uh[i] = (short)h;
          ul[i] = (short)l;
        }
        const int kb = kh * 192 + s6 * 32 + lk * 8;
        bf16x8 bh0 = *(bf16x8*)(&hh[lm * HHP + kb]);
        bf16x8 bl0 = *(bf16x8*)(&hl[lm * HHP + kb]);
        bf16x8 bh1 = *(bf16x8*)(&hh[(16 + lm) * HHP + kb]);
        bf16x8 bl1 = *(bf16x8*)(&hl[(16 + lm) * HHP + kb]);
        acc0 = __builtin_amdgcn_mfma_f32_16x16x32_bf16(uh, bh0, acc0, 0, 0, 0);
        acc0 = __builtin_amdgcn_mfma_f32_16x16x32_bf16(uh, bl0, acc0, 0, 0, 0);
        acc0 = __builtin_amdgcn_mfma_f32_16x16x32_bf16(ul, bh0, acc0, 0, 0, 0);
        acc1 = __builtin_amdgcn_mfma_f32_16x16x32_bf16(uh, bh1, acc1, 0, 0, 0);
        acc1 = __builtin_amdgcn_mfma_f32_16x16x32_bf16(uh, bl1, acc1, 0, 0, 0);
        acc1 = __builtin_amdgcn_mfma_f32_16x16x32_bf16(ul, bh1, acc1, 0, 0, 0);
      }
    }
    __syncthreads();   // h0 reads done; h_lds free for h1
    // ---- stage h1(e-2), then L1 phase B ----
    stage_hpk(h1r, hh, hl, sb, sch);
    __syncthreads();
    if (wL1) {
      #pragma unroll
      for (int s6 = 0; s6 < 6; ++s6) {
        const int kb = kh * 192 + s6 * 32 + lk * 8;
        bf16x8 bh0 = *(bf16x8*)(&hh[lm * HHP + kb]);
        bf16x8 bl0 = *(bf16x8*)(&hl[lm * HHP + kb]);
        bf16x8 bh1 = *(bf16x8*)(&hh[(16 + lm) * HHP + kb]);
        bf16x8 bl1 = *(bf16x8*)(&hl[(16 + lm) * HHP + kb]);
        acc0 = __builtin_amdgcn_mfma_f32_16x16x32_bf16(whi[s6], bh0, acc0, 0, 0, 0);
        acc0 = __builtin_amdgcn_mfma_f32_16x16x32_bf16(whi[s6], bl0, acc0, 0, 0, 0);
        acc0 = __builtin_amdgcn_mfma_f32_16x16x32_bf16(wlo[s6], bh0, acc0, 0, 0, 0);
        acc1 = __builtin_amdgcn_mfma_f32_16x16x32_bf16(whi[s6], bh1, acc1, 0, 0, 0);
        acc1 = __builtin_amdgcn_mfma_f32_16x16x32_bf16(whi[s6], bl1, acc1, 0, 0, 0);
        acc1 = __builtin_amdgcn_mfma_f32_16x16x32_bf16(wlo[s6], bh1, acc1, 0, 0, 0);
      }
      #pragma unroll
      for (int r4 = 0; r4 < 4; ++r4) {
        gsp[wid * 528 + (lk * 4 + r4) * 33 + lm]      = acc0[r4];
        gsp[wid * 528 + (lk * 4 + r4) * 33 + 16 + lm] = acc1[r4];
      }
    }
    __syncthreads();
    // ---- pointwise for both layers ----
    if (tid < 256) {
      if (!pwL1) {
        if (e < NS) {
          float sum[4];
          #pragma unroll
          for (int g = 0; g < 4; ++g) {
            const int row = g * 4 + jloc;
            sum[g] = gsp[0 * 528 + row * 33 + bp] + gsp[1 * 528 + row * 33 + bp] +
                     gsp[2 * 528 + row * 33 + bp] + gsp[3 * 528 + row * 33 + bp];
          }
          const float si = 1.f / (1.f + expf(-(sum[0] + xgv0)));
          const float sf = 1.f / (1.f + expf(-(sum[1] + xgv1)));
          const float so = 1.f / (1.f + expf(-(sum[3] + xgv3)));
          c_reg = sf * c_reg + si * tanhf(sum[2] + xgv2);
          const float hnew = so * tanhf(c_reg);
          unsigned short h16, l16;
          split_bf16(hnew, h16, l16);
          coh_store_u32(&h0pk[(size_t)(e * NB + bp) * NH + lblk * 4 + jloc],
                        ((unsigned)h16 << 16) | l16);
        }
      } else {
        if (e >= 1) {
          const int t = e - 1;
          float sum[4];
          #pragma unroll
          for (int g = 0; g < 4; ++g) {
            const int row = g * 4 + jloc;
            sum[g] = gsp[4 * 528 + row * 33 + bp] + gsp[5 * 528 + row * 33 + bp] +
                     gsp[6 * 528 + row * 33 + bp] + gsp[7 * 528 + row * 33 + bp];
          }
          const float si = 1.f / (1.f + expf(-(sum[0] + bi)));
          const float sf = 1.f / (1.f + expf(-(sum[1] + bf_)));
          const float so = 1.f / (1.f + expf(-(sum[3] + bo)));
          c_reg = sf * c_reg + si * tanhf(sum[2] + bg);
          const float hnew = so * tanhf(c_reg);
          unsigned short h16, l16;
          split_bf16(hnew, h16, l16);
          coh_store_u32(&h1pk[(size_t)(t * NB + bp) * NH + lblk * 4 + jloc],
                        ((unsigned)h16 << 16) | l16);
        }
      }
    }
    // ---- shared grid barrier (epochs 0..63; epoch 64 ends the kernel) ----
    if (e < NS) {
      __syncthreads();
      if (tid == 0) {
        asm volatile("s_waitcnt vmcnt(0)" ::: "memory");
        __hip_atomic_fetch_add(&ctr[(blockIdx.x & (NCTR - 1)) * 16], 1u,
                               __ATOMIC_RELAXED, __HIP_MEMORY_SCOPE_AGENT);
      }
      if (tid < NCTR) {
        const unsigned target = (unsigned)(e + 1) * (FBLK / NCTR);
        while (__hip_atomic_load(&ctr[tid * 16], __ATOMIC_RELAXED,
                                 __HIP_MEMORY_SCOPE_AGENT) < target)
          __builtin_amdgcn_s_sleep(1);
      }
      __syncthreads();
    }
  }
}

// ---------------------------------------------------------------------------
// preds[b*24+s] = dot(unpack(h1pk[s*32+b]), Wout) + bout
// ---------------------------------------------------------------------------
__global__ __launch_bounds__(64) void head_kernel(
    const unsigned* __restrict__ h1pk, const float* __restrict__ Wout,
    const float* __restrict__ bout, float* __restrict__ preds) {
  const int o = blockIdx.x;
  const int b = o / HOR_, s = o % HOR_;
  const int l = threadIdx.x;
  const unsigned* h = h1pk + (size_t)(s * NB + b) * NH;
  float acc = 0.f;
  #pragma unroll
  for (int k = l; k < NH; k += 64) {
    const unsigned w = h[k];
    const float v = __uint_as_float(w & 0xffff0000u) + __uint_as_float(w << 16);
    acc += v * Wout[k];
  }
  #pragma unroll
  for (int m = 32; m; m >>= 1) acc += __shfl_xor(acc, m);
  if (l == 0) preds[o] = acc + bout[0];
}

// ---------------------------------------------------------------------------
extern "C" void kernel_launch(void* const* d_in, const int* in_sizes, int n_in,
                              void* d_out, int out_size, void* d_ws, size_t ws_size,
                              hipStream_t stream) {
  const float* z    = (const float*)d_in[0];
  const float* cond = (const float*)d_in[1];
  const float* encs = (const float*)d_in[2];
  const float* W1   = (const float*)d_in[4];
  const float* b1   = (const float*)d_in[5];
  const float* W2   = (const float*)d_in[6];
  const float* b2   = (const float*)d_in[7];
  const float* Wih0 = (const float*)d_in[8];
  const float* Whh0 = (const float*)d_in[9];
  const float* bih0 = (const float*)d_in[10];
  const float* bhh0 = (const float*)d_in[11];
  const float* Wih1 = (const float*)d_in[12];
  const float* Whh1 = (const float*)d_in[13];
  const float* bih1 = (const float*)d_in[14];
  const float* bhh1 = (const float*)d_in[15];
  const float* Wout = (const float*)d_in[16];
  const float* bout = (const float*)d_in[17];

  float* out     = (float*)d_out;
  float* preds   = out;
  float* enc_out = out + NB * HOR_;

  float* ws    = (float*)d_ws;
  float* xb    = ws + OFF_X;
  float* mean  = ws + OFF_MEAN;
  float* tmp   = ws + OFF_TMP;
  unsigned* h0pk = (unsigned*)(ws + OFF_H0PK);
  unsigned* h1pk = (unsigned*)(ws + OFF_H1PK);
  float* xg    = ws + OFF_XG;
  unsigned* hzero = (unsigned*)(ws + OFF_HZERO);
  unsigned* ctr = (unsigned*)(ws + OFF_CTR);

  // allow >64KB dynamic LDS for the persistent kernel
  (void)hipFuncSetAttribute(reinterpret_cast<const void*>(lstm_merged),
                            hipFuncAttributeMaxDynamicSharedMemorySize,
                            160 * 1024);

  // 1. segment mean (filter and mean are linear and commute -> pool first)
  seg_mean_kernel<<<NSEG_, 192, 0, stream>>>(encs, mean);
  // 2. encoded = (mean @ W1^T + b1) @ W2^T + b2 -> straight into d_out (MFMA)
  gemm_mfma_nt<<<dim3(NH / 64, NSEG_ / 64), 256, 0, stream>>>(
      mean, W1, b1, nullptr, tmp, NSEG_, NH, NH);
  gemm_mfma_nt<<<dim3(NH / 64, NSEG_ / 64), 256, 0, stream>>>(
      tmp, W2, b2, nullptr, enc_out, NSEG_, NH, NH);
  // 3. x = concat(z, cond, encoded), time-major rows (s*32+b)
  build_x_kernel<<<(NSEG_ * NIN) / 256, 256, 0, stream>>>(z, cond, enc_out, xb);
  // 4. layer-0 input gates (biases folded in), K=816 (guarded chunks)
  gemm_mfma_nt<<<dim3(G4 / 64, NSEG_ / 64), 256, 0, stream>>>(
      xb, Wih0, bih0, bhh0, xg, NSEG_, G4, NIN);
  // 5. merged, pipelined 2-layer recurrence (layer-1 xg GEMM folded in)
  hipMemsetAsync(hzero, 0, (size_t)(SZ_HZERO + 16 * 16) * sizeof(float), stream);
  lstm_merged<<<FBLK, LTHR, SMEM_BYTES, stream>>>(
      xg, Whh0, Wih1, Whh1, bih1, bhh1, hzero, h0pk, h1pk, ctr);
  // 6. head
  head_kernel<<<NB * HOR_, 64, 0, stream>>>(h1pk, Wout, bout, preds);
}